// Round 7
// baseline (210.438 us; speedup 1.0000x reference)
//
#include <hip/hip_runtime.h>

typedef float  f4v    __attribute__((ext_vector_type(4)));
typedef __bf16 bf16x8 __attribute__((ext_vector_type(8)));
typedef __bf16 bf16x4 __attribute__((ext_vector_type(4)));

#define PCAP  16384   // max padded pair count (A<=180, P<=16290; P(A>180)~1e-11)
#define LDQ   16384
#define CH    1024
#define KI    2048    // interleaved K
#define KIT   32      // K-iters (BK=64)

__device__ __forceinline__ int offA(int r, int A) { return r * A - ((r * (r - 1)) >> 1); }

// ballot-scan of mask -> act[], A  (caller provides LDS buffers)
__device__ __forceinline__ int mask_scan(const int* am, int t, int* act,
                                         unsigned long long* wm, int* wred) {
    int wave = t >> 6, lane = t & 63;
    int a = am[t];
    int sv = a;
#pragma unroll
    for (int d = 32; d; d >>= 1) sv += __shfl_down(sv, d);
    if (lane == 0) wred[wave] = sv;
    __syncthreads();
    int s = wred[0] + wred[1] + wred[2] + wred[3];
    int keep = (t != 0 && t != s && a != 0) ? 1 : 0;
    unsigned long long bm = __ballot(keep);
    if (lane == 0) wm[wave] = bm;
    __syncthreads();
    int base = 0, A = 0;
#pragma unroll
    for (int w = 0; w < 4; w++) {
        int pc = __popcll(wm[w]);
        if (w < wave) base += pc;
        A += pc;
    }
    if (keep) act[base + __popcll(bm & ((1ull << lane) - 1ull))] = t;
    __syncthreads();
    return A;
}

// ---------------- prep kernel ----------------
#define PB_CVTA   0       // 512: A1p interleaved bf16 conversion of conv1_w
#define PB_K2     512     // 256: K2w[64][1024]
#define PB_QCONST 768     // 49
#define PB_ZERO   817     // 797: zero Q + Qs (contiguous)
#define PB_SCAN   1614    // 1: rank/counts
#define PB_HID    1615    // 256: hid gemv
#define PB_TOTAL  1871

__global__ void k_prep(const float* __restrict__ att, const int* __restrict__ am,
                       const float* __restrict__ c1w, const float* __restrict__ c2w,
                       const float* __restrict__ c1b,
                       const float* __restrict__ pooled, const float* __restrict__ lin1_w,
                       const float* __restrict__ lin1_b,
                       int* rank, int* counts, __bf16* A1p, __bf16* K2w,
                       float* Qc, float* Qzero, float* hid) {
    int b = blockIdx.x, t = threadIdx.x;
    if (b < PB_K2) {
        int gid = b * 256 + t;              // 131072 total
        int o = gid >> 7, cw = (gid & 127) * 8;
        const float* wd = &c1w[o * 2048 + cw];
        const float* wmu = &c1w[o * 2048 + 1024 + cw];
        float4 d0 = *(const float4*)wd,  d1 = *(const float4*)(wd + 4);
        float4 m0 = *(const float4*)wmu, m1 = *(const float4*)(wmu + 4);
        bf16x8 v0, v1;
        v0[0] = (__bf16)d0.x; v0[1] = (__bf16)m0.x; v0[2] = (__bf16)d0.y; v0[3] = (__bf16)m0.y;
        v0[4] = (__bf16)d0.z; v0[5] = (__bf16)m0.z; v0[6] = (__bf16)d0.w; v0[7] = (__bf16)m0.w;
        v1[0] = (__bf16)d1.x; v1[1] = (__bf16)m1.x; v1[2] = (__bf16)d1.y; v1[3] = (__bf16)m1.y;
        v1[4] = (__bf16)d1.z; v1[5] = (__bf16)m1.z; v1[6] = (__bf16)d1.w; v1[7] = (__bf16)m1.w;
        *(bf16x8*)&A1p[o * 2048 + 2 * cw] = v0;
        *(bf16x8*)&A1p[o * 2048 + 2 * cw + 8] = v1;
    } else if (b < PB_QCONST) {
        int e = (b - PB_K2) * 256 + t;      // 65536 = 64*1024
        int trow = e >> 10, o = e & 1023;
        K2w[e] = (trow < 49) ? (__bf16)c2w[o * 49 + trow] : (__bf16)0.0f;
    } else if (b < PB_ZERO) {
        __shared__ float sh[256];
        int tap = b - PB_QCONST;
        float s = 0.f;
        for (int o = t; o < CH; o += 256) s += c2w[o * 49 + tap] * fmaxf(c1b[o], 0.f);
        sh[t] = s; __syncthreads();
        for (int d = 128; d; d >>= 1) { if (t < d) sh[t] += sh[t + d]; __syncthreads(); }
        if (t == 0) Qc[tap] = sh[0];
    } else if (b < PB_SCAN) {
        int idx = (b - PB_ZERO) * 256 + t;  // 203840 float4 = Q(49*16384) + Qs(49*256)
        if (idx < 203840) {
            float4 zv = {0.f, 0.f, 0.f, 0.f};
            ((float4*)Qzero)[idx] = zv;
        }
    } else if (b == PB_SCAN) {
        __shared__ int act[256];
        __shared__ unsigned long long wm[4];
        __shared__ int wred[4];
        int A = mask_scan(am, t, act, wm, wred);
        int wave = t >> 6, lane = t & 63;
        int s = wred[0] + wred[1] + wred[2] + wred[3];
        int keep = (t != 0 && t != s && am[t] != 0) ? 1 : 0;
        int base = 0;
#pragma unroll
        for (int w = 0; w < 4; w++) if (w < wave) base += __popcll(wm[w]);
        unsigned long long bm = wm[wave];
        rank[t] = keep ? (base + __popcll(bm & ((1ull << lane) - 1ull))) : -1;
        if (t == 0) {
            int P = (A * (A + 1)) >> 1;
            int Pp = ((P + 127) >> 7) << 7;
            if (Pp > PCAP) Pp = PCAP;
            counts[0] = A; counts[1] = P; counts[2] = Pp;
        }
    } else {
        int o = (b - PB_HID) * 4 + (t >> 6);
        int lane = t & 63;
        const float* row = lin1_w + (size_t)o * CH;
        float s = 0.f;
        for (int c = lane; c < CH; c += 64) s += pooled[c] * row[c];
        for (int d = 32; d; d >>= 1) s += __shfl_down(s, d);
        if (lane == 0) hid[o] = s + lin1_b[o];
    }
}

// ---------------- fused GEMM: B-build + GEMM1 + relu + GEMM2-partial ----------------
// grid (9, 130): x<8 -> mb=x (XCD = x%8); x==8 -> logits gemv.
// y<128: full-pair tiles (gated by Ppad); y in {128,129}: single-column tiles.
__global__ __launch_bounds__(256) void gemm_fused(
        const float* __restrict__ att, const int* __restrict__ am,
        const __bf16* __restrict__ A1p, const __bf16* __restrict__ K2w,
        const float* __restrict__ c1b,
        float* __restrict__ Q, float* __restrict__ Qs,
        const float* __restrict__ hid, const float* __restrict__ cls_w,
        const float* __restrict__ cls_b, float* __restrict__ logits) {
    int mbx = blockIdx.x, nb = blockIdx.y;
    int tid = threadIdx.x, wave = tid >> 6, lane = tid & 63;
    if (mbx == 8) {
        // logits gemv: 130 blocks x 16 rows (4 per wave)
#pragma unroll
        for (int rr = 0; rr < 4; rr++) {
            int o = nb * 16 + wave * 4 + rr;
            if (o >= 2000) break;
            const float* row = cls_w + (size_t)o * CH;
            float s = 0.f;
            for (int c = lane; c < CH; c += 64) s += hid[c] * row[c];
            for (int d = 32; d; d >>= 1) s += __shfl_down(s, d);
            if (lane == 0) logits[o] = s + cls_b[o];
        }
        return;
    }
    int mb = mbx;
    bool sing = (nb >= 128);

    __shared__ __align__(16) char smemraw[65536];       // As/Bs dbuf | hTL+K2L overlay
    __shared__ int piL[128], pjL[128];
    __shared__ int act[256];
    __shared__ unsigned long long wm[4];
    __shared__ int wred[4];

// inline LDS tile addressing (no stored addrspacecast pointers)
#define ASP(bsel) ((__bf16(*)[64])(smemraw + (bsel) * 16384))
#define BSP(bsel) ((__bf16(*)[64])(smemraw + 32768 + (bsel) * 16384))
#define HTL ((__bf16(*)[136])(smemraw))
#define K2L ((__bf16(*)[136])(smemraw + 34816))

    if (!sing) {
        int A = mask_scan(am, tid, act, wm, wred);
        int P = (A * (A + 1)) >> 1;
        int Ppad = ((P + 127) >> 7) << 7;
        if (Ppad > PCAP) Ppad = PCAP;
        if (nb * 128 >= Ppad) return;                   // uniform
        if (tid < 128 && A > 0) {
            int n = nb * 128 + tid;
            if (n >= P) n = P - 1;                      // pad rows: duplicate last pair
            float fA = (float)(2 * A + 1);
            float disc = fmaxf(fA * fA - 8.0f * (float)n, 0.0f);
            int r = (int)floorf((fA - sqrtf(disc)) * 0.5f);
            r = min(A - 1, max(0, r));
            while (r > 0 && offA(r, A) > n) --r;
            while (r < A - 1 && offA(r + 1, A) <= n) ++r;
            piL[tid] = act[r];
            pjL[tid] = act[r + (n - offA(r, A))];
        }
    }
    __syncthreads();

    // per-thread B-build setup: thread = (pair bn, half)
    int bn = tid >> 1, half = tid & 1;
    const float *ai, *aj = nullptr;
    if (sing) {
        int q = (nb - 128) * 128 + bn;
        ai = att + q * CH + half * 16;
    } else {
        ai = att + piL[bn] * CH + half * 16;
        aj = att + pjL[bn] * CH + half * 16;
    }

    // A staging (global_load_lds): wave w covers rows w*32..w*32+31, 4 instrs x 8 rows
    int lanerow = lane >> 3;
    int swchunk = ((lane & 7) ^ lanerow) * 8;
    const __bf16* srcA = A1p + (size_t)(mb * 128 + wave * 32 + lanerow) * KI + swchunk;

    f4v acc[4][4] = {};
    int row16 = lane & 15, quad = lane >> 4;
    int wx = wave & 1, wy = wave >> 1;

#define STAGE_A(kt, bsel)                                                         \
    _Pragma("unroll")                                                             \
    for (int q = 0; q < 4; q++) {                                                 \
        __builtin_amdgcn_global_load_lds(                                         \
            (const __attribute__((address_space(1))) void*)(srcA + (size_t)q * 8 * KI + (kt) * 64), \
            (__attribute__((address_space(3))) void*)&ASP(bsel)[wave * 32 + q * 8][0], 16, 0, 0); \
    }

#define LOAD_B(kt)                                                                \
    {                                                                             \
        const float* pa = ai + (kt) * 32;                                         \
        ba0 = *(const float4*)pa; ba1 = *(const float4*)(pa + 4);                 \
        ba2 = *(const float4*)(pa + 8); ba3 = *(const float4*)(pa + 12);          \
        if (!sing) {                                                              \
            const float* pb = aj + (kt) * 32;                                     \
            bb0 = *(const float4*)pb; bb1 = *(const float4*)(pb + 4);             \
            bb2 = *(const float4*)(pb + 8); bb3 = *(const float4*)(pb + 12);      \
        }                                                                         \
    }

#define BUILD_B(bsel)                                                             \
    {                                                                             \
        float4 aa[4] = {ba0, ba1, ba2, ba3};                                      \
        float4 bbv[4] = {bb0, bb1, bb2, bb3};                                     \
        _Pragma("unroll")                                                         \
        for (int u = 0; u < 4; u++) {                                             \
            float4 a = aa[u];                                                     \
            bf16x8 v;                                                             \
            if (sing) {                                                           \
                v[0] = (__bf16)fabsf(a.x); v[1] = (__bf16)0.f;                    \
                v[2] = (__bf16)fabsf(a.y); v[3] = (__bf16)0.f;                    \
                v[4] = (__bf16)fabsf(a.z); v[5] = (__bf16)0.f;                    \
                v[6] = (__bf16)fabsf(a.w); v[7] = (__bf16)0.f;                    \
            } else {                                                              \
                float4 b = bbv[u];                                                \
                v[0] = (__bf16)fabsf(a.x - b.x); v[1] = (__bf16)(a.x * b.x);      \
                v[2] = (__bf16)fabsf(a.y - b.y); v[3] = (__bf16)(a.y * b.y);      \
                v[4] = (__bf16)fabsf(a.z - b.z); v[5] = (__bf16)(a.z * b.z);      \
                v[6] = (__bf16)fabsf(a.w - b.w); v[7] = (__bf16)(a.w * b.w);      \
            }                                                                     \
            *(bf16x8*)&BSP(bsel)[bn][(((half * 4 + u) ^ (bn & 7)) * 8)] = v;      \
        }                                                                         \
    }

    float4 ba0, ba1, ba2, ba3, bb0, bb1, bb2, bb3;
    ba0 = ba1 = ba2 = ba3 = bb0 = bb1 = bb2 = bb3 = float4{0.f, 0.f, 0.f, 0.f};

    // prologue: fill buffer 0
    LOAD_B(0);
    STAGE_A(0, 0);
    BUILD_B(0);
    __syncthreads();

    for (int kt = 0; kt < KIT; ++kt) {
        int cur = kt & 1, nxt = cur ^ 1;
        if (kt + 1 < KIT) {
            LOAD_B(kt + 1);
            STAGE_A(kt + 1, nxt);
        }
        // MFMA on cur
#pragma unroll
        for (int ks = 0; ks < 2; ks++) {
            bf16x8 a[4], b[4];
            int col = ((ks * 4 + quad) ^ (row16 & 7)) * 8;
#pragma unroll
            for (int mt = 0; mt < 4; mt++)
                a[mt] = *(const bf16x8*)&ASP(cur)[wy * 64 + mt * 16 + row16][col];
#pragma unroll
            for (int nt = 0; nt < 4; nt++)
                b[nt] = *(const bf16x8*)&BSP(cur)[wx * 64 + nt * 16 + row16][col];
#pragma unroll
            for (int mt = 0; mt < 4; mt++)
#pragma unroll
                for (int nt = 0; nt < 4; nt++)
                    acc[mt][nt] = __builtin_amdgcn_mfma_f32_16x16x32_bf16(a[mt], b[nt], acc[mt][nt], 0, 0, 0);
        }
        if (kt + 1 < KIT) BUILD_B(nxt);
        __syncthreads();
    }

    // ---- phase 2: hTile -> LDS, K2 tile -> LDS, contract o-local 128 ----
    // stage K2 tile [64 t][128 o] via regs (padded rows)
#pragma unroll
    for (int it = 0; it < 4; it++) {
        int gid = it * 256 + tid;                  // 1024 = 64 rows x 16 chunks
        int trow = gid >> 4, oc = (gid & 15) * 8;
        bf16x8 kv = *(const bf16x8*)&K2w[(size_t)trow * CH + mb * 128 + oc];
        *(bf16x8*)&K2L[trow][oc] = kv;
    }
    // write relu(acc + bias) tiles into hTL[n][o]
#pragma unroll
    for (int mt = 0; mt < 4; mt++) {
        int ol = wy * 64 + mt * 16 + quad * 4;
        float4 bv = *(const float4*)&c1b[mb * 128 + ol];
#pragma unroll
        for (int nt = 0; nt < 4; nt++) {
            int n = wx * 64 + nt * 16 + row16;
            bf16x4 pk;
            pk[0] = (__bf16)fmaxf(acc[mt][nt][0] + bv.x, 0.f);
            pk[1] = (__bf16)fmaxf(acc[mt][nt][1] + bv.y, 0.f);
            pk[2] = (__bf16)fmaxf(acc[mt][nt][2] + bv.z, 0.f);
            pk[3] = (__bf16)fmaxf(acc[mt][nt][3] + bv.w, 0.f);
            *(bf16x4*)&HTL[n][ol] = pk;
        }
    }
    __syncthreads();

    f4v acc2[8] = {};
#pragma unroll
    for (int ko = 0; ko < 4; ko++) {
        bf16x8 af = *(const bf16x8*)&K2L[wave * 16 + row16][ko * 32 + quad * 8];
#pragma unroll
        for (int nt = 0; nt < 8; nt++) {
            bf16x8 bf_ = *(const bf16x8*)&HTL[nt * 16 + row16][ko * 32 + quad * 8];
            acc2[nt] = __builtin_amdgcn_mfma_f32_16x16x32_bf16(af, bf_, acc2[nt], 0, 0, 0);
        }
    }

    float* Qdst = sing ? Qs : Q;
    int ldq = sing ? 256 : LDQ;
    int nbase = sing ? (nb - 128) * 128 : nb * 128;
    int t0 = wave * 16 + quad * 4;
#pragma unroll
    for (int nt = 0; nt < 8; nt++) {
        int n = nbase + nt * 16 + row16;
#pragma unroll
        for (int r = 0; r < 4; r++)
            if (t0 + r < 49) atomicAdd(&Qdst[(size_t)(t0 + r) * ldq + n], acc2[nt][r]);
    }
#undef ASP
#undef BSP
#undef HTL
#undef K2L
#undef STAGE_A
#undef LOAD_B
#undef BUILD_B
}

// ---------------- output: one thread per (i,j) ----------------
__global__ void k_out(const float* __restrict__ Q, const float* __restrict__ Qs,
                      const float* __restrict__ Qc, const int* __restrict__ rank,
                      const int* __restrict__ counts, const float* b2,
                      float* __restrict__ outmaps) {
    __shared__ int rankL[256];
    __shared__ float QcL[49];
    int t = threadIdx.x, i = blockIdx.x;
    rankL[t] = rank[t];
    if (t < 49) QcL[t] = Qc[t];
    __syncthreads();
    int A = counts[0];
    int j = t;
    float acc = b2[0];
#pragma unroll
    for (int di = 0; di < 7; di++) {
        int p = i + di - 3;
        if ((unsigned)p > 255u) continue;
#pragma unroll
        for (int dj = 0; dj < 7; dj++) {
            int q = j + dj - 3;
            if ((unsigned)q > 255u) continue;
            int tt = di * 7 + dj;
            int a = min(p, q), bb = max(p, q);
            int ra = rankL[a], rb = rankL[bb];
            float val;
            if (ra >= 0) val = (rb >= 0) ? Q[(size_t)tt * LDQ + offA(ra, A) + (rb - ra)]
                                         : Qs[tt * 256 + a];
            else         val = (rb >= 0) ? Qs[tt * 256 + bb] : QcL[tt];
            acc += val;
        }
    }
    outmaps[i * 256 + j] = 1.0f / (1.0f + expf(-acc));
}

// ---------------- launch ----------------

extern "C" void kernel_launch(void* const* d_in, const int* in_sizes, int n_in,
                              void* d_out, int out_size, void* d_ws, size_t ws_size,
                              hipStream_t stream) {
    const float* att    = (const float*)d_in[0];
    const float* pooled = (const float*)d_in[1];
    const int*   am     = (const int*)d_in[2];
    const float* lin1_w = (const float*)d_in[3];
    const float* lin1_b = (const float*)d_in[4];
    const float* cls_w  = (const float*)d_in[5];
    const float* cls_b  = (const float*)d_in[6];
    const float* c1w    = (const float*)d_in[7];
    const float* c1b    = (const float*)d_in[8];
    const float* c2w    = (const float*)d_in[9];
    const float* c2b    = (const float*)d_in[10];
    float* out = (float*)d_out;
    char*  ws  = (char*)d_ws;

    // workspace (~7.6 MB)
    __bf16* A1p  = (__bf16*)(ws);                 // 1024*2048*2 = 4,194,304
    __bf16* K2w  = (__bf16*)(ws + 4194304);       // 64*1024*2   =   131,072
    float*  Q    = (float*) (ws + 4325376);       // 49*16384*4  = 3,211,264
    float*  Qs   = (float*) (ws + 7536640);       // 49*256*4    =    50,176
    float*  Qc   = (float*) (ws + 7586816);       // 49*4 (pad 256)
    int*    rank = (int*)   (ws + 7587072);       // 256*4 (pad 1024)
    float*  hid  = (float*) (ws + 7588096);       // 1024*4
    int*    counts=(int*)   (ws + 7592192);       // 16*4

    k_prep<<<PB_TOTAL, 256, 0, stream>>>(att, am, c1w, c2w, c1b, pooled, lin1_w, lin1_b,
                                         rank, counts, A1p, K2w, Qc, Q /*zero base*/, hid);

    gemm_fused<<<dim3(9, 130), 256, 0, stream>>>(att, am, A1p, K2w, c1b, Q, Qs,
                                                 hid, cls_w, cls_b, out);

    k_out<<<256, 256, 0, stream>>>(Q, Qs, Qc, rank, counts, c2b, out + 2000);
}

// Round 8
// 171.216 us; speedup vs baseline: 1.2291x; 1.2291x over previous
//
#include <hip/hip_runtime.h>

typedef float  f4v    __attribute__((ext_vector_type(4)));
typedef __bf16 bf16x8 __attribute__((ext_vector_type(8)));
typedef __bf16 bf16x4 __attribute__((ext_vector_type(4)));

#define PCAP  16384   // max padded pair count (A<=180; actual A~127 -> Ppad 8192)
#define LDQ   16384
#define CH    1024
#define KI    2048    // interleaved K (diff/mul alternating)
#define KIT   32      // K iterations (BK=64)

__device__ __forceinline__ int offA(int r, int A) { return r * A - ((r * (r - 1)) >> 1); }

// ballot-scan of mask -> act[], A
__device__ __forceinline__ int mask_scan(const int* am, int t, int* act,
                                         unsigned long long* wm, int* wred) {
    int wave = t >> 6, lane = t & 63;
    int a = am[t];
    int sv = a;
#pragma unroll
    for (int d = 32; d; d >>= 1) sv += __shfl_down(sv, d);
    if (lane == 0) wred[wave] = sv;
    __syncthreads();
    int s = wred[0] + wred[1] + wred[2] + wred[3];
    int keep = (t != 0 && t != s && a != 0) ? 1 : 0;
    unsigned long long bm = __ballot(keep);
    if (lane == 0) wm[wave] = bm;
    __syncthreads();
    int base = 0, A = 0;
#pragma unroll
    for (int w = 0; w < 4; w++) {
        int pc = __popcll(wm[w]);
        if (w < wave) base += pc;
        A += pc;
    }
    if (keep) act[base + __popcll(bm & ((1ull << lane) - 1ull))] = t;
    __syncthreads();
    return A;
}

// ---------------- prep kernel: blockIdx ranges ----------------
#define PB_FEATP  0       // 2048: pair featT rows (8/block), self-scan
#define PB_FEATS  2048    // 32: single featT rows at [PCAP, PCAP+256)
#define PB_CVTA   2080    // 512: A1p interleaved bf16 conv of conv1_w
#define PB_K2     2592    // 256: K2w[64][1024]
#define PB_QCONST 2848    // 49
#define PB_ZERO   2897    // 797: zero Q + Qs (contiguous)
#define PB_SCAN   3694    // 1: rank/counts
#define PB_HID    3695    // 256: hid gemv
#define PB_TOTAL  3951

__global__ void k_prep(const float* __restrict__ att, const int* __restrict__ am,
                       const float* __restrict__ c1w, const float* __restrict__ c2w,
                       const float* __restrict__ c1b,
                       const float* __restrict__ pooled, const float* __restrict__ lin1_w,
                       const float* __restrict__ lin1_b,
                       int* rank, int* counts, __bf16* featT, __bf16* A1p, __bf16* K2w,
                       float* Qc, float* Qzero, float* hid) {
    int b = blockIdx.x, t = threadIdx.x;

    if (b < PB_FEATS) {
        // ---- pair featT rows: interleaved K, unified layout ----
        __shared__ int act[256];
        __shared__ unsigned long long wm[4];
        __shared__ int wred[4];
        int A = mask_scan(am, t, act, wm, wred);
        int P = (A * (A + 1)) >> 1;
        int Ppad = ((P + 127) >> 7) << 7;
        if (Ppad > PCAP) { Ppad = PCAP; P = PCAP; }
        int n0 = b * 8;
        if (n0 >= Ppad) return;
        int c0 = t * 4;                    // 4 original channels per thread
        float fA = (float)(2 * A + 1);
        for (int q = 0; q < 8; q++) {
            int n = n0 + q;
            bf16x8 ov;
            if (n < P && A > 0) {
                float disc = fmaxf(fA * fA - 8.0f * (float)n, 0.0f);
                int r = (int)floorf((fA - sqrtf(disc)) * 0.5f);
                r = min(A - 1, max(0, r));
                while (r > 0 && offA(r, A) > n) --r;
                while (r < A - 1 && offA(r + 1, A) <= n) ++r;
                int i = act[r], j = act[r + (n - offA(r, A))];
                float4 a = *(const float4*)&att[i * CH + c0];
                float4 bj = *(const float4*)&att[j * CH + c0];
                ov[0] = (__bf16)fabsf(a.x - bj.x); ov[1] = (__bf16)(a.x * bj.x);
                ov[2] = (__bf16)fabsf(a.y - bj.y); ov[3] = (__bf16)(a.y * bj.y);
                ov[4] = (__bf16)fabsf(a.z - bj.z); ov[5] = (__bf16)(a.z * bj.z);
                ov[6] = (__bf16)fabsf(a.w - bj.w); ov[7] = (__bf16)(a.w * bj.w);
            } else {
#pragma unroll
                for (int r8 = 0; r8 < 8; r8++) ov[r8] = (__bf16)0.0f;
            }
            *(bf16x8*)&featT[(size_t)n * KI + t * 8] = ov;
        }
    } else if (b < PB_CVTA) {
        // ---- single featT rows: |att[r]| at even slots, 0 at odd ----
        int r0 = (b - PB_FEATS) * 8;
        int c0 = t * 4;
        for (int q = 0; q < 8; q++) {
            int r = r0 + q;
            float4 a = *(const float4*)&att[r * CH + c0];
            bf16x8 ov;
            ov[0] = (__bf16)fabsf(a.x); ov[1] = (__bf16)0.f;
            ov[2] = (__bf16)fabsf(a.y); ov[3] = (__bf16)0.f;
            ov[4] = (__bf16)fabsf(a.z); ov[5] = (__bf16)0.f;
            ov[6] = (__bf16)fabsf(a.w); ov[7] = (__bf16)0.f;
            *(bf16x8*)&featT[(size_t)(PCAP + r) * KI + t * 8] = ov;
        }
    } else if (b < PB_K2) {
        int gid = (b - PB_CVTA) * 256 + t;  // 131072
        int o = gid >> 7, cw = (gid & 127) * 8;
        const float* wd = &c1w[o * 2048 + cw];
        const float* wmu = &c1w[o * 2048 + 1024 + cw];
        float4 d0 = *(const float4*)wd,  d1 = *(const float4*)(wd + 4);
        float4 m0 = *(const float4*)wmu, m1 = *(const float4*)(wmu + 4);
        bf16x8 v0, v1;
        v0[0] = (__bf16)d0.x; v0[1] = (__bf16)m0.x; v0[2] = (__bf16)d0.y; v0[3] = (__bf16)m0.y;
        v0[4] = (__bf16)d0.z; v0[5] = (__bf16)m0.z; v0[6] = (__bf16)d0.w; v0[7] = (__bf16)m0.w;
        v1[0] = (__bf16)d1.x; v1[1] = (__bf16)m1.x; v1[2] = (__bf16)d1.y; v1[3] = (__bf16)m1.y;
        v1[4] = (__bf16)d1.z; v1[5] = (__bf16)m1.z; v1[6] = (__bf16)d1.w; v1[7] = (__bf16)m1.w;
        *(bf16x8*)&A1p[o * 2048 + 2 * cw] = v0;
        *(bf16x8*)&A1p[o * 2048 + 2 * cw + 8] = v1;
    } else if (b < PB_QCONST) {
        int e = (b - PB_K2) * 256 + t;      // 65536 = 64*1024
        int trow = e >> 10, o = e & 1023;
        K2w[e] = (trow < 49) ? (__bf16)c2w[o * 49 + trow] : (__bf16)0.0f;
    } else if (b < PB_ZERO) {
        __shared__ float sh[256];
        int tap = b - PB_QCONST;
        float s = 0.f;
        for (int o = t; o < CH; o += 256) s += c2w[o * 49 + tap] * fmaxf(c1b[o], 0.f);
        sh[t] = s; __syncthreads();
        for (int d = 128; d; d >>= 1) { if (t < d) sh[t] += sh[t + d]; __syncthreads(); }
        if (t == 0) Qc[tap] = sh[0];
    } else if (b < PB_SCAN) {
        int idx = (b - PB_ZERO) * 256 + t;  // 203840 float4 = Q(49*16384) + Qs(49*256)
        if (idx < 203840) {
            float4 zv = {0.f, 0.f, 0.f, 0.f};
            ((float4*)Qzero)[idx] = zv;
        }
    } else if (b == PB_SCAN) {
        __shared__ int act[256];
        __shared__ unsigned long long wm[4];
        __shared__ int wred[4];
        int A = mask_scan(am, t, act, wm, wred);
        int wave = t >> 6, lane = t & 63;
        int s = wred[0] + wred[1] + wred[2] + wred[3];
        int keep = (t != 0 && t != s && am[t] != 0) ? 1 : 0;
        int base = 0;
#pragma unroll
        for (int w = 0; w < 4; w++) if (w < wave) base += __popcll(wm[w]);
        unsigned long long bm = wm[wave];
        rank[t] = keep ? (base + __popcll(bm & ((1ull << lane) - 1ull))) : -1;
        if (t == 0) {
            int P = (A * (A + 1)) >> 1;
            int Pp = ((P + 127) >> 7) << 7;
            if (Pp > PCAP) Pp = PCAP;
            counts[0] = A; counts[1] = P; counts[2] = Pp;
        }
    } else {
        int o = (b - PB_HID) * 4 + (t >> 6);
        int lane = t & 63;
        const float* row = lin1_w + (size_t)o * CH;
        float s = 0.f;
        for (int c = lane; c < CH; c += 64) s += pooled[c] * row[c];
        for (int d = 32; d; d >>= 1) s += __shfl_down(s, d);
        if (lane == 0) hid[o] = s + lin1_b[o];
    }
}

// ---------------- GEMM: 128x128, BK=64, dbuf, vmcnt(8), XCD N-partition ----------------
// grid (9, 136). x<8: GEMM blocks; XCD g=(x+y)&7 owns nb = g*c_rt + y/8, mb = y&7.
// x==8: logits gemv (136 blocks x 15 rows).
// Epilogue: in-LDS GEMM2 (K2 taps) -> atomicAdd into Q / Qs.
__global__ __launch_bounds__(256) void gemm_fused(
        const __bf16* __restrict__ A1p, const __bf16* __restrict__ featT,
        const __bf16* __restrict__ K2w, const float* __restrict__ c1b,
        const int* __restrict__ counts,
        float* __restrict__ Q, float* __restrict__ Qs,
        const float* __restrict__ hid, const float* __restrict__ cls_w,
        const float* __restrict__ cls_b, float* __restrict__ logits) {
    int x = blockIdx.x, y = blockIdx.y;
    int tid = threadIdx.x, wave = tid >> 6, lane = tid & 63;

    if (x == 8) {
        for (int rr = wave; rr < 15; rr += 4) {
            int o = y * 15 + rr;
            if (o >= 2000) break;
            const float* row = cls_w + (size_t)o * CH;
            float s = 0.f;
            for (int c = lane; c < CH; c += 64) s += hid[c] * row[c];
            for (int d = 32; d; d >>= 1) s += __shfl_down(s, d);
            if (lane == 0) logits[o] = s + cls_b[o];
        }
        return;
    }

    int Ppad = counts[2];
    int ntp = Ppad >> 7;                 // pair tiles
    int ntiles = ntp + 2;                // + 2 single tiles
    int c_rt = (ntiles + 7) >> 3;
    int g = (x + y) & 7;
    int nbl = y >> 3, mb = y & 7;
    if (nbl >= c_rt) return;
    int nb = g * c_rt + nbl;
    if (nb >= ntiles) return;
    bool sing = (nb >= ntp);
    int brow = sing ? (PCAP + (nb - ntp) * 128) : nb * 128;

    __shared__ __align__(16) char smemraw[65536];
#define ASP(bsel) ((__bf16(*)[64])(smemraw + (bsel) * 16384))
#define BSP(bsel) ((__bf16(*)[64])(smemraw + 32768 + (bsel) * 16384))
#define HTL ((__bf16(*)[136])(smemraw))
#define K2L ((__bf16(*)[136])(smemraw + 34816))

    // staging: wave0/1 -> A rows 0-63/64-127, wave2/3 -> B rows 0-63/64-127
    int isB = wave >> 1;
    int rowbase = (wave & 1) * 64;
    int lanerow = lane >> 3;
    int swchunk = ((lane & 7) ^ lanerow) * 8;
    const __bf16* G = isB ? (featT + (size_t)brow * KI)
                          : (A1p + (size_t)mb * 128 * KI);
    const __bf16* srcbase = G + (size_t)(rowbase + lanerow) * KI + swchunk;

    f4v acc[4][4] = {};
    int row16 = lane & 15, quad = lane >> 4;
    int wx = wave & 1, wy = wave >> 1;

#define STAGE(kt, bsel)                                                           \
    {                                                                             \
        const __bf16* sP = srcbase + (kt) * 64;                                   \
        _Pragma("unroll")                                                         \
        for (int q = 0; q < 8; q++) {                                             \
            __bf16* dP = isB ? &BSP(bsel)[rowbase + q * 8][0]                     \
                             : &ASP(bsel)[rowbase + q * 8][0];                    \
            __builtin_amdgcn_global_load_lds(                                     \
                (const __attribute__((address_space(1))) void*)(sP + (size_t)q * 8 * KI), \
                (__attribute__((address_space(3))) void*)dP, 16, 0, 0);           \
        }                                                                         \
    }

    STAGE(0, 0);
    for (int kt = 0; kt < KIT; ++kt) {
        int cur = kt & 1;
        if (kt + 1 < KIT) {
            STAGE(kt + 1, cur ^ 1);
            __builtin_amdgcn_s_waitcnt(0xF78);   // vmcnt(8): prev batch done, next in flight
        } else {
            __builtin_amdgcn_s_waitcnt(0xF70);   // vmcnt(0)
        }
        __builtin_amdgcn_s_barrier();
#pragma unroll
        for (int ks = 0; ks < 2; ks++) {
            bf16x8 a[4], b[4];
            int col = ((ks * 4 + quad) ^ (row16 & 7)) * 8;
#pragma unroll
            for (int mt = 0; mt < 4; mt++)
                a[mt] = *(const bf16x8*)&ASP(cur)[wy * 64 + mt * 16 + row16][col];
#pragma unroll
            for (int nt = 0; nt < 4; nt++)
                b[nt] = *(const bf16x8*)&BSP(cur)[wx * 64 + nt * 16 + row16][col];
#pragma unroll
            for (int mt = 0; mt < 4; mt++)
#pragma unroll
                for (int nt = 0; nt < 4; nt++)
                    acc[mt][nt] = __builtin_amdgcn_mfma_f32_16x16x32_bf16(a[mt], b[nt], acc[mt][nt], 0, 0, 0);
        }
        __builtin_amdgcn_s_barrier();
    }
#undef STAGE

    // ---- phase 2: K2 tile + relu(h) tile in LDS, contract 128 local o's ----
#pragma unroll
    for (int it = 0; it < 4; it++) {
        int gid = it * 256 + tid;                  // 1024 = 64 rows x 16 chunks
        int trow = gid >> 4, oc = (gid & 15) * 8;
        bf16x8 kv = *(const bf16x8*)&K2w[(size_t)trow * CH + mb * 128 + oc];
        *(bf16x8*)&K2L[trow][oc] = kv;
    }
#pragma unroll
    for (int mt = 0; mt < 4; mt++) {
        int ol = wy * 64 + mt * 16 + quad * 4;
        float4 bv = *(const float4*)&c1b[mb * 128 + ol];
#pragma unroll
        for (int nt = 0; nt < 4; nt++) {
            int n = wx * 64 + nt * 16 + row16;
            bf16x4 pk;
            pk[0] = (__bf16)fmaxf(acc[mt][nt][0] + bv.x, 0.f);
            pk[1] = (__bf16)fmaxf(acc[mt][nt][1] + bv.y, 0.f);
            pk[2] = (__bf16)fmaxf(acc[mt][nt][2] + bv.z, 0.f);
            pk[3] = (__bf16)fmaxf(acc[mt][nt][3] + bv.w, 0.f);
            *(bf16x4*)&HTL[n][ol] = pk;
        }
    }
    __syncthreads();

    f4v acc2[8] = {};
#pragma unroll
    for (int ko = 0; ko < 4; ko++) {
        bf16x8 af = *(const bf16x8*)&K2L[wave * 16 + row16][ko * 32 + quad * 8];
#pragma unroll
        for (int nt = 0; nt < 8; nt++) {
            bf16x8 bf_ = *(const bf16x8*)&HTL[nt * 16 + row16][ko * 32 + quad * 8];
            acc2[nt] = __builtin_amdgcn_mfma_f32_16x16x32_bf16(af, bf_, acc2[nt], 0, 0, 0);
        }
    }

    float* Qdst = sing ? Qs : Q;
    int ldq = sing ? 256 : LDQ;
    int nbase = sing ? (nb - ntp) * 128 : nb * 128;
    int t0 = wave * 16 + quad * 4;
#pragma unroll
    for (int nt = 0; nt < 8; nt++) {
        int n = nbase + nt * 16 + row16;
#pragma unroll
        for (int r = 0; r < 4; r++)
            if (t0 + r < 49) atomicAdd(&Qdst[(size_t)(t0 + r) * ldq + n], acc2[nt][r]);
    }
#undef ASP
#undef BSP
#undef HTL
#undef K2L
}

// ---------------- output: one thread per (i,j) ----------------
__global__ void k_out(const float* __restrict__ Q, const float* __restrict__ Qs,
                      const float* __restrict__ Qc, const int* __restrict__ rank,
                      const int* __restrict__ counts, const float* b2,
                      float* __restrict__ outmaps) {
    __shared__ int rankL[256];
    __shared__ float QcL[49];
    int t = threadIdx.x, i = blockIdx.x;
    rankL[t] = rank[t];
    if (t < 49) QcL[t] = Qc[t];
    __syncthreads();
    int A = counts[0];
    int j = t;
    float acc = b2[0];
#pragma unroll
    for (int di = 0; di < 7; di++) {
        int p = i + di - 3;
        if ((unsigned)p > 255u) continue;
#pragma unroll
        for (int dj = 0; dj < 7; dj++) {
            int q = j + dj - 3;
            if ((unsigned)q > 255u) continue;
            int tt = di * 7 + dj;
            int a = min(p, q), bb = max(p, q);
            int ra = rankL[a], rb = rankL[bb];
            float val;
            if (ra >= 0) val = (rb >= 0) ? Q[(size_t)tt * LDQ + offA(ra, A) + (rb - ra)]
                                         : Qs[tt * 256 + a];
            else         val = (rb >= 0) ? Qs[tt * 256 + bb] : QcL[tt];
            acc += val;
        }
    }
    outmaps[i * 256 + j] = 1.0f / (1.0f + expf(-acc));
}

// ---------------- launch ----------------

extern "C" void kernel_launch(void* const* d_in, const int* in_sizes, int n_in,
                              void* d_out, int out_size, void* d_ws, size_t ws_size,
                              hipStream_t stream) {
    const float* att    = (const float*)d_in[0];
    const float* pooled = (const float*)d_in[1];
    const int*   am     = (const int*)d_in[2];
    const float* lin1_w = (const float*)d_in[3];
    const float* lin1_b = (const float*)d_in[4];
    const float* cls_w  = (const float*)d_in[5];
    const float* cls_b  = (const float*)d_in[6];
    const float* c1w    = (const float*)d_in[7];
    const float* c1b    = (const float*)d_in[8];
    const float* c2w    = (const float*)d_in[9];
    const float* c2b    = (const float*)d_in[10];
    float* out = (float*)d_out;
    char*  ws  = (char*)d_ws;

    // workspace (~75.8 MB)
    __bf16* A1p  = (__bf16*)(ws);                 // 1024*2048*2 = 4,194,304
    __bf16* K2w  = (__bf16*)(ws + 4194304);       // 64*1024*2   =   131,072
    float*  Q    = (float*) (ws + 4325376);       // 49*16384*4  = 3,211,264
    float*  Qs   = (float*) (ws + 7536640);       // 49*256*4    =    50,176  (contiguous with Q)
    float*  Qc   = (float*) (ws + 7586816);       // 49*4 (pad 256)
    int*    rank = (int*)   (ws + 7587072);       // 256*4 (pad 1024)
    float*  hid  = (float*) (ws + 7588096);       // 1024*4
    int*    counts=(int*)   (ws + 7592192);       // 16*4 (pad to 768)
    __bf16* featT= (__bf16*)(ws + 7592960);       // (PCAP+256)*2048*2 = 68,157,440

    k_prep<<<PB_TOTAL, 256, 0, stream>>>(att, am, c1w, c2w, c1b, pooled, lin1_w, lin1_b,
                                         rank, counts, featT, A1p, K2w, Qc, Q, hid);

    gemm_fused<<<dim3(9, 136), 256, 0, stream>>>(A1p, featT, K2w, c1b, counts, Q, Qs,
                                                 hid, cls_w, cls_b, out);

    k_out<<<256, 256, 0, stream>>>(Q, Qs, Qc, rank, counts, c2b, out + 2000);
}

// Round 9
// 163.118 us; speedup vs baseline: 1.2901x; 1.0496x over previous
//
#include <hip/hip_runtime.h>

typedef float  f4v    __attribute__((ext_vector_type(4)));
typedef __bf16 bf16x8 __attribute__((ext_vector_type(8)));
typedef __bf16 bf16x4 __attribute__((ext_vector_type(4)));

#define PCAP  16384   // max padded pair count (A<=180; actual A~127 -> Ppad 8192)
#define LDQ   16384
#define CH    1024
#define KI    2048    // interleaved K (diff/mul alternating)
#define KIT   32      // K iterations (BK=64)

__device__ __forceinline__ int offA(int r, int A) { return r * A - ((r * (r - 1)) >> 1); }

// ballot-scan of mask -> act[], A
__device__ __forceinline__ int mask_scan(const int* am, int t, int* act,
                                         unsigned long long* wm, int* wred) {
    int wave = t >> 6, lane = t & 63;
    int a = am[t];
    int sv = a;
#pragma unroll
    for (int d = 32; d; d >>= 1) sv += __shfl_down(sv, d);
    if (lane == 0) wred[wave] = sv;
    __syncthreads();
    int s = wred[0] + wred[1] + wred[2] + wred[3];
    int keep = (t != 0 && t != s && a != 0) ? 1 : 0;
    unsigned long long bm = __ballot(keep);
    if (lane == 0) wm[wave] = bm;
    __syncthreads();
    int base = 0, A = 0;
#pragma unroll
    for (int w = 0; w < 4; w++) {
        int pc = __popcll(wm[w]);
        if (w < wave) base += pc;
        A += pc;
    }
    if (keep) act[base + __popcll(bm & ((1ull << lane) - 1ull))] = t;
    __syncthreads();
    return A;
}

// ---------------- prep kernel: blockIdx ranges ----------------
#define PB_FEATP  0       // 2048: pair featT rows (8/block), self-scan
#define PB_FEATS  2048    // 32: single featT rows at [PCAP, PCAP+256)
#define PB_CVTA   2080    // 512: A1p interleaved bf16 conv of conv1_w
#define PB_K2     2592    // 256: K2w[64][1024]
#define PB_QCONST 2848    // 49
#define PB_ZERO   2897    // 797: zero Q + Qs (contiguous)
#define PB_SCAN   3694    // 1: rank/counts
#define PB_HID    3695    // 256: hid gemv
#define PB_TOTAL  3951

__global__ void k_prep(const float* __restrict__ att, const int* __restrict__ am,
                       const float* __restrict__ c1w, const float* __restrict__ c2w,
                       const float* __restrict__ c1b,
                       const float* __restrict__ pooled, const float* __restrict__ lin1_w,
                       const float* __restrict__ lin1_b,
                       int* rank, int* counts, __bf16* featT, __bf16* A1p, __bf16* K2w,
                       float* Qc, float* Qzero, float* hid) {
    int b = blockIdx.x, t = threadIdx.x;

    if (b < PB_FEATS) {
        // ---- pair featT rows: interleaved K, unified layout ----
        __shared__ int act[256];
        __shared__ unsigned long long wm[4];
        __shared__ int wred[4];
        int A = mask_scan(am, t, act, wm, wred);
        int P = (A * (A + 1)) >> 1;
        int Ppad = ((P + 127) >> 7) << 7;
        if (Ppad > PCAP) { Ppad = PCAP; P = PCAP; }
        int n0 = b * 8;
        if (n0 >= Ppad) return;
        int c0 = t * 4;                    // 4 original channels per thread
        float fA = (float)(2 * A + 1);
        for (int q = 0; q < 8; q++) {
            int n = n0 + q;
            bf16x8 ov;
            if (n < P && A > 0) {
                float disc = fmaxf(fA * fA - 8.0f * (float)n, 0.0f);
                int r = (int)floorf((fA - sqrtf(disc)) * 0.5f);
                r = min(A - 1, max(0, r));
                while (r > 0 && offA(r, A) > n) --r;
                while (r < A - 1 && offA(r + 1, A) <= n) ++r;
                int i = act[r], j = act[r + (n - offA(r, A))];
                float4 a = *(const float4*)&att[i * CH + c0];
                float4 bj = *(const float4*)&att[j * CH + c0];
                ov[0] = (__bf16)fabsf(a.x - bj.x); ov[1] = (__bf16)(a.x * bj.x);
                ov[2] = (__bf16)fabsf(a.y - bj.y); ov[3] = (__bf16)(a.y * bj.y);
                ov[4] = (__bf16)fabsf(a.z - bj.z); ov[5] = (__bf16)(a.z * bj.z);
                ov[6] = (__bf16)fabsf(a.w - bj.w); ov[7] = (__bf16)(a.w * bj.w);
            } else {
#pragma unroll
                for (int r8 = 0; r8 < 8; r8++) ov[r8] = (__bf16)0.0f;
            }
            *(bf16x8*)&featT[(size_t)n * KI + t * 8] = ov;
        }
    } else if (b < PB_CVTA) {
        // ---- single featT rows: |att[r]| at even slots, 0 at odd ----
        int r0 = (b - PB_FEATS) * 8;
        int c0 = t * 4;
        for (int q = 0; q < 8; q++) {
            int r = r0 + q;
            float4 a = *(const float4*)&att[r * CH + c0];
            bf16x8 ov;
            ov[0] = (__bf16)fabsf(a.x); ov[1] = (__bf16)0.f;
            ov[2] = (__bf16)fabsf(a.y); ov[3] = (__bf16)0.f;
            ov[4] = (__bf16)fabsf(a.z); ov[5] = (__bf16)0.f;
            ov[6] = (__bf16)fabsf(a.w); ov[7] = (__bf16)0.f;
            *(bf16x8*)&featT[(size_t)(PCAP + r) * KI + t * 8] = ov;
        }
    } else if (b < PB_K2) {
        int gid = (b - PB_CVTA) * 256 + t;  // 131072
        int o = gid >> 7, cw = (gid & 127) * 8;
        const float* wd = &c1w[o * 2048 + cw];
        const float* wmu = &c1w[o * 2048 + 1024 + cw];
        float4 d0 = *(const float4*)wd,  d1 = *(const float4*)(wd + 4);
        float4 m0 = *(const float4*)wmu, m1 = *(const float4*)(wmu + 4);
        bf16x8 v0, v1;
        v0[0] = (__bf16)d0.x; v0[1] = (__bf16)m0.x; v0[2] = (__bf16)d0.y; v0[3] = (__bf16)m0.y;
        v0[4] = (__bf16)d0.z; v0[5] = (__bf16)m0.z; v0[6] = (__bf16)d0.w; v0[7] = (__bf16)m0.w;
        v1[0] = (__bf16)d1.x; v1[1] = (__bf16)m1.x; v1[2] = (__bf16)d1.y; v1[3] = (__bf16)m1.y;
        v1[4] = (__bf16)d1.z; v1[5] = (__bf16)m1.z; v1[6] = (__bf16)d1.w; v1[7] = (__bf16)m1.w;
        *(bf16x8*)&A1p[o * 2048 + 2 * cw] = v0;
        *(bf16x8*)&A1p[o * 2048 + 2 * cw + 8] = v1;
    } else if (b < PB_QCONST) {
        int e = (b - PB_K2) * 256 + t;      // 65536 = 64*1024
        int trow = e >> 10, o = e & 1023;
        K2w[e] = (trow < 49) ? (__bf16)c2w[o * 49 + trow] : (__bf16)0.0f;
    } else if (b < PB_ZERO) {
        __shared__ float sh[256];
        int tap = b - PB_QCONST;
        float s = 0.f;
        for (int o = t; o < CH; o += 256) s += c2w[o * 49 + tap] * fmaxf(c1b[o], 0.f);
        sh[t] = s; __syncthreads();
        for (int d = 128; d; d >>= 1) { if (t < d) sh[t] += sh[t + d]; __syncthreads(); }
        if (t == 0) Qc[tap] = sh[0];
    } else if (b < PB_SCAN) {
        int idx = (b - PB_ZERO) * 256 + t;  // 203840 float4 = Q(49*16384) + Qs(49*256)
        if (idx < 203840) {
            float4 zv = {0.f, 0.f, 0.f, 0.f};
            ((float4*)Qzero)[idx] = zv;
        }
    } else if (b == PB_SCAN) {
        __shared__ int act[256];
        __shared__ unsigned long long wm[4];
        __shared__ int wred[4];
        int A = mask_scan(am, t, act, wm, wred);
        int wave = t >> 6, lane = t & 63;
        int s = wred[0] + wred[1] + wred[2] + wred[3];
        int keep = (t != 0 && t != s && am[t] != 0) ? 1 : 0;
        int base = 0;
#pragma unroll
        for (int w = 0; w < 4; w++) if (w < wave) base += __popcll(wm[w]);
        unsigned long long bm = wm[wave];
        rank[t] = keep ? (base + __popcll(bm & ((1ull << lane) - 1ull))) : -1;
        if (t == 0) {
            int P = (A * (A + 1)) >> 1;
            int Pp = ((P + 127) >> 7) << 7;
            if (Pp > PCAP) Pp = PCAP;
            counts[0] = A; counts[1] = P; counts[2] = Pp;
        }
    } else {
        int o = (b - PB_HID) * 4 + (t >> 6);
        int lane = t & 63;
        const float* row = lin1_w + (size_t)o * CH;
        float s = 0.f;
        for (int c = lane; c < CH; c += 64) s += pooled[c] * row[c];
        for (int d = 32; d; d >>= 1) s += __shfl_down(s, d);
        if (lane == 0) hid[o] = s + lin1_b[o];
    }
}

// ---------------- GEMM: 128M x 64N, BK=64, dbuf, vmcnt(6), XCD N-partition ----------------
// grid (9, 264). x<8: GEMM blocks; XCD g=(x+y)&7 owns nb = g*c_rt + (y>>3), mb = y&7.
// x==8: logits gemv (8 rows/block).
// Epilogue: in-LDS GEMM2 (K2 taps, 64 n-cols) -> atomicAdd into Q / Qs.
__global__ __launch_bounds__(256) void gemm_fused(
        const __bf16* __restrict__ A1p, const __bf16* __restrict__ featT,
        const __bf16* __restrict__ K2w, const float* __restrict__ c1b,
        const int* __restrict__ counts,
        float* __restrict__ Q, float* __restrict__ Qs,
        const float* __restrict__ hid, const float* __restrict__ cls_w,
        const float* __restrict__ cls_b, float* __restrict__ logits) {
    int x = blockIdx.x, y = blockIdx.y;
    int tid = threadIdx.x, wave = tid >> 6, lane = tid & 63;

    if (x == 8) {
        for (int rr = wave; rr < 8; rr += 4) {
            int o = y * 8 + rr;
            if (o >= 2000) break;
            const float* row = cls_w + (size_t)o * CH;
            float s = 0.f;
            for (int c = lane; c < CH; c += 64) s += hid[c] * row[c];
            for (int d = 32; d; d >>= 1) s += __shfl_down(s, d);
            if (lane == 0) logits[o] = s + cls_b[o];
        }
        return;
    }

    int Ppad = counts[2];
    int ntp = Ppad >> 6;                 // 64-col pair tiles
    int ntiles = ntp + 4;                // + 4 single tiles (256 rows)
    int c_rt = (ntiles + 7) >> 3;
    int g = (x + y) & 7;
    int nbl = y >> 3, mb = y & 7;
    if (nbl >= c_rt) return;
    int nb = g * c_rt + nbl;
    if (nb >= ntiles) return;
    bool sing = (nb >= ntp);
    int brow = sing ? (PCAP + (nb - ntp) * 64) : nb * 64;

    __shared__ __align__(16) char smemraw[49152];
#define ASP(bsel) ((__bf16(*)[64])(smemraw + (bsel) * 16384))
#define BSP(bsel) ((__bf16(*)[64])(smemraw + 32768 + (bsel) * 8192))
#define HTL ((__bf16(*)[136])(smemraw))
#define K2L ((__bf16(*)[136])(smemraw + 17408))

    // staging: each wave stages A rows [w*32,w*32+32) (4 instr) + B rows [w*16,w*16+16) (2 instr)
    int lanerow = lane >> 3;
    int swchunk = ((lane & 7) ^ lanerow) * 8;
    const __bf16* srcA = A1p + (size_t)(mb * 128 + wave * 32 + lanerow) * KI + swchunk;
    const __bf16* srcB = featT + (size_t)(brow + wave * 16 + lanerow) * KI + swchunk;

    f4v acc[4][2] = {};
    int row16 = lane & 15, quad = lane >> 4;
    int wx = wave & 1, wy = wave >> 1;

#define STAGE(kt, bsel)                                                           \
    {                                                                             \
        const __bf16* sA = srcA + (kt) * 64;                                      \
        _Pragma("unroll")                                                         \
        for (int q = 0; q < 4; q++) {                                             \
            __builtin_amdgcn_global_load_lds(                                     \
                (const __attribute__((address_space(1))) void*)(sA + (size_t)q * 8 * KI), \
                (__attribute__((address_space(3))) void*)&ASP(bsel)[wave * 32 + q * 8][0], 16, 0, 0); \
        }                                                                         \
        const __bf16* sB = srcB + (kt) * 64;                                      \
        _Pragma("unroll")                                                         \
        for (int q = 0; q < 2; q++) {                                             \
            __builtin_amdgcn_global_load_lds(                                     \
                (const __attribute__((address_space(1))) void*)(sB + (size_t)q * 8 * KI), \
                (__attribute__((address_space(3))) void*)&BSP(bsel)[wave * 16 + q * 8][0], 16, 0, 0); \
        }                                                                         \
    }

    STAGE(0, 0);
    for (int kt = 0; kt < KIT; ++kt) {
        int cur = kt & 1;
        if (kt + 1 < KIT) {
            STAGE(kt + 1, cur ^ 1);
            __builtin_amdgcn_s_waitcnt(0xF76);   // vmcnt(6): prev batch done, next in flight
        } else {
            __builtin_amdgcn_s_waitcnt(0xF70);   // vmcnt(0)
        }
        __builtin_amdgcn_s_barrier();
#pragma unroll
        for (int ks = 0; ks < 2; ks++) {
            bf16x8 a[4], b[2];
            int col = ((ks * 4 + quad) ^ (row16 & 7)) * 8;
#pragma unroll
            for (int mt = 0; mt < 4; mt++)
                a[mt] = *(const bf16x8*)&ASP(cur)[wy * 64 + mt * 16 + row16][col];
#pragma unroll
            for (int nt = 0; nt < 2; nt++)
                b[nt] = *(const bf16x8*)&BSP(cur)[wx * 32 + nt * 16 + row16][col];
#pragma unroll
            for (int mt = 0; mt < 4; mt++)
#pragma unroll
                for (int nt = 0; nt < 2; nt++)
                    acc[mt][nt] = __builtin_amdgcn_mfma_f32_16x16x32_bf16(a[mt], b[nt], acc[mt][nt], 0, 0, 0);
        }
        __builtin_amdgcn_s_barrier();
    }
#undef STAGE

    // ---- phase 2: K2 tile + relu(h) tile in LDS, contract 128 local o's ----
#pragma unroll
    for (int it = 0; it < 4; it++) {
        int gid = it * 256 + tid;                  // 1024 = 64 rows x 16 chunks
        int trow = gid >> 4, oc = (gid & 15) * 8;
        bf16x8 kv = *(const bf16x8*)&K2w[(size_t)trow * CH + mb * 128 + oc];
        *(bf16x8*)&K2L[trow][oc] = kv;
    }
#pragma unroll
    for (int mt = 0; mt < 4; mt++) {
        int ol = wy * 64 + mt * 16 + quad * 4;
        float4 bv = *(const float4*)&c1b[mb * 128 + ol];
#pragma unroll
        for (int nt = 0; nt < 2; nt++) {
            int n = wx * 32 + nt * 16 + row16;
            bf16x4 pk;
            pk[0] = (__bf16)fmaxf(acc[mt][nt][0] + bv.x, 0.f);
            pk[1] = (__bf16)fmaxf(acc[mt][nt][1] + bv.y, 0.f);
            pk[2] = (__bf16)fmaxf(acc[mt][nt][2] + bv.z, 0.f);
            pk[3] = (__bf16)fmaxf(acc[mt][nt][3] + bv.w, 0.f);
            *(bf16x4*)&HTL[n][ol] = pk;
        }
    }
    __syncthreads();

    f4v acc2[4] = {};
#pragma unroll
    for (int ko = 0; ko < 4; ko++) {
        bf16x8 af = *(const bf16x8*)&K2L[wave * 16 + row16][ko * 32 + quad * 8];
#pragma unroll
        for (int nt = 0; nt < 4; nt++) {
            bf16x8 bf_ = *(const bf16x8*)&HTL[nt * 16 + row16][ko * 32 + quad * 8];
            acc2[nt] = __builtin_amdgcn_mfma_f32_16x16x32_bf16(af, bf_, acc2[nt], 0, 0, 0);
        }
    }

    float* Qdst = sing ? Qs : Q;
    int ldq = sing ? 256 : LDQ;
    int nbase = sing ? (nb - ntp) * 64 : nb * 64;
    int t0 = wave * 16 + quad * 4;
#pragma unroll
    for (int nt = 0; nt < 4; nt++) {
        int n = nbase + nt * 16 + row16;
#pragma unroll
        for (int r = 0; r < 4; r++)
            if (t0 + r < 49) atomicAdd(&Qdst[(size_t)(t0 + r) * ldq + n], acc2[nt][r]);
    }
#undef ASP
#undef BSP
#undef HTL
#undef K2L
}

// ---------------- output: one thread per (i,j) ----------------
__global__ void k_out(const float* __restrict__ Q, const float* __restrict__ Qs,
                      const float* __restrict__ Qc, const int* __restrict__ rank,
                      const int* __restrict__ counts, const float* b2,
                      float* __restrict__ outmaps) {
    __shared__ int rankL[256];
    __shared__ float QcL[49];
    int t = threadIdx.x, i = blockIdx.x;
    rankL[t] = rank[t];
    if (t < 49) QcL[t] = Qc[t];
    __syncthreads();
    int A = counts[0];
    int j = t;
    float acc = b2[0];
#pragma unroll
    for (int di = 0; di < 7; di++) {
        int p = i + di - 3;
        if ((unsigned)p > 255u) continue;
#pragma unroll
        for (int dj = 0; dj < 7; dj++) {
            int q = j + dj - 3;
            if ((unsigned)q > 255u) continue;
            int tt = di * 7 + dj;
            int a = min(p, q), bb = max(p, q);
            int ra = rankL[a], rb = rankL[bb];
            float val;
            if (ra >= 0) val = (rb >= 0) ? Q[(size_t)tt * LDQ + offA(ra, A) + (rb - ra)]
                                         : Qs[tt * 256 + a];
            else         val = (rb >= 0) ? Qs[tt * 256 + bb] : QcL[tt];
            acc += val;
        }
    }
    outmaps[i * 256 + j] = 1.0f / (1.0f + expf(-acc));
}

// ---------------- launch ----------------

extern "C" void kernel_launch(void* const* d_in, const int* in_sizes, int n_in,
                              void* d_out, int out_size, void* d_ws, size_t ws_size,
                              hipStream_t stream) {
    const float* att    = (const float*)d_in[0];
    const float* pooled = (const float*)d_in[1];
    const int*   am     = (const int*)d_in[2];
    const float* lin1_w = (const float*)d_in[3];
    const float* lin1_b = (const float*)d_in[4];
    const float* cls_w  = (const float*)d_in[5];
    const float* cls_b  = (const float*)d_in[6];
    const float* c1w    = (const float*)d_in[7];
    const float* c1b    = (const float*)d_in[8];
    const float* c2w    = (const float*)d_in[9];
    const float* c2b    = (const float*)d_in[10];
    float* out = (float*)d_out;
    char*  ws  = (char*)d_ws;

    // workspace (~75.8 MB)
    __bf16* A1p  = (__bf16*)(ws);                 // 1024*2048*2 = 4,194,304
    __bf16* K2w  = (__bf16*)(ws + 4194304);       // 64*1024*2   =   131,072
    float*  Q    = (float*) (ws + 4325376);       // 49*16384*4  = 3,211,264
    float*  Qs   = (float*) (ws + 7536640);       // 49*256*4    =    50,176  (contiguous with Q)
    float*  Qc   = (float*) (ws + 7586816);       // 49*4 (pad 256)
    int*    rank = (int*)   (ws + 7587072);       // 256*4 (pad 1024)
    float*  hid  = (float*) (ws + 7588096);       // 1024*4
    int*    counts=(int*)   (ws + 7592192);       // 16*4 (pad to 768)
    __bf16* featT= (__bf16*)(ws + 7592960);       // (PCAP+256)*2048*2 = 68,157,440

    k_prep<<<PB_TOTAL, 256, 0, stream>>>(att, am, c1w, c2w, c1b, pooled, lin1_w, lin1_b,
                                         rank, counts, featT, A1p, K2w, Qc, Q, hid);

    gemm_fused<<<dim3(9, 264), 256, 0, stream>>>(A1p, featT, K2w, c1b, counts, Q, Qs,
                                                 hid, cls_w, cls_b, out);

    k_out<<<256, 256, 0, stream>>>(Q, Qs, Qc, rank, counts, c2b, out + 2000);
}

// Round 10
// 163.041 us; speedup vs baseline: 1.2907x; 1.0005x over previous
//
#include <hip/hip_runtime.h>

typedef float  f4v    __attribute__((ext_vector_type(4)));
typedef __bf16 bf16x8 __attribute__((ext_vector_type(8)));
typedef __bf16 bf16x4 __attribute__((ext_vector_type(4)));

#define PCAP  16384   // max padded pair count (A<=180; actual A~127 -> Ppad 8192)
#define LDQ   16384
#define CH    1024
#define KI    2048    // interleaved K (diff/mul alternating)
#define KIT   32      // K iterations (BK=64)

__device__ __forceinline__ int offA(int r, int A) { return r * A - ((r * (r - 1)) >> 1); }

// ballot-scan of mask -> act[], A
__device__ __forceinline__ int mask_scan(const int* am, int t, int* act,
                                         unsigned long long* wm, int* wred) {
    int wave = t >> 6, lane = t & 63;
    int a = am[t];
    int sv = a;
#pragma unroll
    for (int d = 32; d; d >>= 1) sv += __shfl_down(sv, d);
    if (lane == 0) wred[wave] = sv;
    __syncthreads();
    int s = wred[0] + wred[1] + wred[2] + wred[3];
    int keep = (t != 0 && t != s && a != 0) ? 1 : 0;
    unsigned long long bm = __ballot(keep);
    if (lane == 0) wm[wave] = bm;
    __syncthreads();
    int base = 0, A = 0;
#pragma unroll
    for (int w = 0; w < 4; w++) {
        int pc = __popcll(wm[w]);
        if (w < wave) base += pc;
        A += pc;
    }
    if (keep) act[base + __popcll(bm & ((1ull << lane) - 1ull))] = t;
    __syncthreads();
    return A;
}

// ---------------- prep kernel: blockIdx ranges ----------------
#define PB_FEATP  0       // 2048: pair featT rows (8/block), self-scan
#define PB_FEATS  2048    // 32: single featT rows at [PCAP, PCAP+256)
#define PB_CVTA   2080    // 512: A1p interleaved bf16 conv of conv1_w
#define PB_K2     2592    // 256: K2w[64][1024]
#define PB_QCONST 2848    // 49
#define PB_ZERO   2897    // 797: zero Q + Qs (contiguous)
#define PB_SCAN   3694    // 1: rank/counts
#define PB_HID    3695    // 256: hid gemv
#define PB_TOTAL  3951

__global__ void k_prep(const float* __restrict__ att, const int* __restrict__ am,
                       const float* __restrict__ c1w, const float* __restrict__ c2w,
                       const float* __restrict__ c1b,
                       const float* __restrict__ pooled, const float* __restrict__ lin1_w,
                       const float* __restrict__ lin1_b,
                       int* rank, int* counts, __bf16* featT, __bf16* A1p, __bf16* K2w,
                       float* Qc, float* Qzero, float* hid) {
    int b = blockIdx.x, t = threadIdx.x;

    if (b < PB_FEATS) {
        // ---- pair featT rows: interleaved K, unified layout ----
        __shared__ int act[256];
        __shared__ unsigned long long wm[4];
        __shared__ int wred[4];
        int A = mask_scan(am, t, act, wm, wred);
        int P = (A * (A + 1)) >> 1;
        int Ppad = ((P + 127) >> 7) << 7;
        if (Ppad > PCAP) { Ppad = PCAP; P = PCAP; }
        int n0 = b * 8;
        if (n0 >= Ppad) return;
        int c0 = t * 4;                    // 4 original channels per thread
        float fA = (float)(2 * A + 1);
        for (int q = 0; q < 8; q++) {
            int n = n0 + q;
            bf16x8 ov;
            if (n < P && A > 0) {
                float disc = fmaxf(fA * fA - 8.0f * (float)n, 0.0f);
                int r = (int)floorf((fA - sqrtf(disc)) * 0.5f);
                r = min(A - 1, max(0, r));
                while (r > 0 && offA(r, A) > n) --r;
                while (r < A - 1 && offA(r + 1, A) <= n) ++r;
                int i = act[r], j = act[r + (n - offA(r, A))];
                float4 a = *(const float4*)&att[i * CH + c0];
                float4 bj = *(const float4*)&att[j * CH + c0];
                ov[0] = (__bf16)fabsf(a.x - bj.x); ov[1] = (__bf16)(a.x * bj.x);
                ov[2] = (__bf16)fabsf(a.y - bj.y); ov[3] = (__bf16)(a.y * bj.y);
                ov[4] = (__bf16)fabsf(a.z - bj.z); ov[5] = (__bf16)(a.z * bj.z);
                ov[6] = (__bf16)fabsf(a.w - bj.w); ov[7] = (__bf16)(a.w * bj.w);
            } else {
#pragma unroll
                for (int r8 = 0; r8 < 8; r8++) ov[r8] = (__bf16)0.0f;
            }
            *(bf16x8*)&featT[(size_t)n * KI + t * 8] = ov;
        }
    } else if (b < PB_CVTA) {
        // ---- single featT rows: |att[r]| at even slots, 0 at odd ----
        int r0 = (b - PB_FEATS) * 8;
        int c0 = t * 4;
        for (int q = 0; q < 8; q++) {
            int r = r0 + q;
            float4 a = *(const float4*)&att[r * CH + c0];
            bf16x8 ov;
            ov[0] = (__bf16)fabsf(a.x); ov[1] = (__bf16)0.f;
            ov[2] = (__bf16)fabsf(a.y); ov[3] = (__bf16)0.f;
            ov[4] = (__bf16)fabsf(a.z); ov[5] = (__bf16)0.f;
            ov[6] = (__bf16)fabsf(a.w); ov[7] = (__bf16)0.f;
            *(bf16x8*)&featT[(size_t)(PCAP + r) * KI + t * 8] = ov;
        }
    } else if (b < PB_K2) {
        int gid = (b - PB_CVTA) * 256 + t;  // 131072
        int o = gid >> 7, cw = (gid & 127) * 8;
        const float* wd = &c1w[o * 2048 + cw];
        const float* wmu = &c1w[o * 2048 + 1024 + cw];
        float4 d0 = *(const float4*)wd,  d1 = *(const float4*)(wd + 4);
        float4 m0 = *(const float4*)wmu, m1 = *(const float4*)(wmu + 4);
        bf16x8 v0, v1;
        v0[0] = (__bf16)d0.x; v0[1] = (__bf16)m0.x; v0[2] = (__bf16)d0.y; v0[3] = (__bf16)m0.y;
        v0[4] = (__bf16)d0.z; v0[5] = (__bf16)m0.z; v0[6] = (__bf16)d0.w; v0[7] = (__bf16)m0.w;
        v1[0] = (__bf16)d1.x; v1[1] = (__bf16)m1.x; v1[2] = (__bf16)d1.y; v1[3] = (__bf16)m1.y;
        v1[4] = (__bf16)d1.z; v1[5] = (__bf16)m1.z; v1[6] = (__bf16)d1.w; v1[7] = (__bf16)m1.w;
        *(bf16x8*)&A1p[o * 2048 + 2 * cw] = v0;
        *(bf16x8*)&A1p[o * 2048 + 2 * cw + 8] = v1;
    } else if (b < PB_QCONST) {
        int e = (b - PB_K2) * 256 + t;      // 65536 = 64*1024
        int trow = e >> 10, o = e & 1023;
        K2w[e] = (trow < 49) ? (__bf16)c2w[o * 49 + trow] : (__bf16)0.0f;
    } else if (b < PB_ZERO) {
        __shared__ float sh[256];
        int tap = b - PB_QCONST;
        float s = 0.f;
        for (int o = t; o < CH; o += 256) s += c2w[o * 49 + tap] * fmaxf(c1b[o], 0.f);
        sh[t] = s; __syncthreads();
        for (int d = 128; d; d >>= 1) { if (t < d) sh[t] += sh[t + d]; __syncthreads(); }
        if (t == 0) Qc[tap] = sh[0];
    } else if (b < PB_SCAN) {
        int idx = (b - PB_ZERO) * 256 + t;  // 203840 float4 = Q(49*16384) + Qs(49*256)
        if (idx < 203840) {
            float4 zv = {0.f, 0.f, 0.f, 0.f};
            ((float4*)Qzero)[idx] = zv;
        }
    } else if (b == PB_SCAN) {
        __shared__ int act[256];
        __shared__ unsigned long long wm[4];
        __shared__ int wred[4];
        int A = mask_scan(am, t, act, wm, wred);
        int wave = t >> 6, lane = t & 63;
        int s = wred[0] + wred[1] + wred[2] + wred[3];
        int keep = (t != 0 && t != s && am[t] != 0) ? 1 : 0;
        int base = 0;
#pragma unroll
        for (int w = 0; w < 4; w++) if (w < wave) base += __popcll(wm[w]);
        unsigned long long bm = wm[wave];
        rank[t] = keep ? (base + __popcll(bm & ((1ull << lane) - 1ull))) : -1;
        if (t == 0) {
            int P = (A * (A + 1)) >> 1;
            int Pp = ((P + 127) >> 7) << 7;
            if (Pp > PCAP) Pp = PCAP;
            counts[0] = A; counts[1] = P; counts[2] = Pp;
        }
    } else {
        int o = (b - PB_HID) * 4 + (t >> 6);
        int lane = t & 63;
        const float* row = lin1_w + (size_t)o * CH;
        float s = 0.f;
        for (int c = lane; c < CH; c += 64) s += pooled[c] * row[c];
        for (int d = 32; d; d >>= 1) s += __shfl_down(s, d);
        if (lane == 0) hid[o] = s + lin1_b[o];
    }
}

// ---------------- GEMM: 512 threads, 128M x 128N, BK=64, dbuf, vmcnt(4) ----------------
// grid (9, 130). x<8: GEMM; mb=(x+y)&7 == XCD id (linear id x+9y mod 8) -> A-slice hot per XCD.
// nb = y (exit if y >= ntiles). x==8: logits gemv (16 rows/block).
// Epilogue: in-LDS GEMM2 (K2 taps, 128 n-cols) -> atomicAdd into Q / Qs.
__global__ __launch_bounds__(512) void gemm_fused(
        const __bf16* __restrict__ A1p, const __bf16* __restrict__ featT,
        const __bf16* __restrict__ K2w, const float* __restrict__ c1b,
        const int* __restrict__ counts,
        float* __restrict__ Q, float* __restrict__ Qs,
        const float* __restrict__ hid, const float* __restrict__ cls_w,
        const float* __restrict__ cls_b, float* __restrict__ logits) {
    int x = blockIdx.x, y = blockIdx.y;
    int tid = threadIdx.x, wave = tid >> 6, lane = tid & 63;

    if (x == 8) {
#pragma unroll
        for (int rr = 0; rr < 2; rr++) {
            int o = y * 16 + wave * 2 + rr;
            if (o >= 2000) break;
            const float* row = cls_w + (size_t)o * CH;
            float s = 0.f;
            for (int c = lane; c < CH; c += 64) s += hid[c] * row[c];
            for (int d = 32; d; d >>= 1) s += __shfl_down(s, d);
            if (lane == 0) logits[o] = s + cls_b[o];
        }
        return;
    }

    int Ppad = counts[2];
    int ntp = Ppad >> 7;                 // 128-col pair tiles
    int ntiles = ntp + 2;                // + 2 single tiles (256 rows)
    int nb = y;
    if (nb >= ntiles) return;
    int mb = (x + y) & 7;                // == XCD id under linear id (x + 9y) % 8
    bool sing = (nb >= ntp);
    int brow = sing ? (PCAP + (nb - ntp) * 128) : nb * 128;

    __shared__ __align__(16) char smemraw[65536];
#define ASP(bsel) ((__bf16(*)[64])(smemraw + (bsel) * 16384))
#define BSP(bsel) ((__bf16(*)[64])(smemraw + 32768 + (bsel) * 16384))
#define HTL ((__bf16(*)[136])(smemraw))
#define K2L ((__bf16(*)[136])(smemraw + 34816))

    // staging: wave w stages A rows [w*16, w*16+16) and B rows [w*16, w*16+16), 2 instr each
    int lanerow = lane >> 3;
    int swchunk = ((lane & 7) ^ lanerow) * 8;
    const __bf16* srcA = A1p + (size_t)(mb * 128 + wave * 16 + lanerow) * KI + swchunk;
    const __bf16* srcB = featT + (size_t)(brow + wave * 16 + lanerow) * KI + swchunk;

    f4v acc[4][2] = {};
    int row16 = lane & 15, quad = lane >> 4;
    int wx = wave & 3, wy = wave >> 2;   // wave tile: rows wy*64+mt*16, cols wx*32+nt*16

#define STAGE(kt, bsel)                                                           \
    {                                                                             \
        const __bf16* sA = srcA + (kt) * 64;                                      \
        _Pragma("unroll")                                                         \
        for (int q = 0; q < 2; q++) {                                             \
            __builtin_amdgcn_global_load_lds(                                     \
                (const __attribute__((address_space(1))) void*)(sA + (size_t)q * 8 * KI), \
                (__attribute__((address_space(3))) void*)&ASP(bsel)[wave * 16 + q * 8][0], 16, 0, 0); \
        }                                                                         \
        const __bf16* sB = srcB + (kt) * 64;                                      \
        _Pragma("unroll")                                                         \
        for (int q = 0; q < 2; q++) {                                             \
            __builtin_amdgcn_global_load_lds(                                     \
                (const __attribute__((address_space(1))) void*)(sB + (size_t)q * 8 * KI), \
                (__attribute__((address_space(3))) void*)&BSP(bsel)[wave * 16 + q * 8][0], 16, 0, 0); \
        }                                                                         \
    }

    STAGE(0, 0);
    for (int kt = 0; kt < KIT; ++kt) {
        int cur = kt & 1;
        if (kt + 1 < KIT) {
            STAGE(kt + 1, cur ^ 1);
            __builtin_amdgcn_s_waitcnt(0xF74);   // vmcnt(4): prev batch done, next in flight
        } else {
            __builtin_amdgcn_s_waitcnt(0xF70);   // vmcnt(0)
        }
        __builtin_amdgcn_s_barrier();
#pragma unroll
        for (int ks = 0; ks < 2; ks++) {
            bf16x8 a[4], b[2];
            int col = ((ks * 4 + quad) ^ (row16 & 7)) * 8;
#pragma unroll
            for (int mt = 0; mt < 4; mt++)
                a[mt] = *(const bf16x8*)&ASP(cur)[wy * 64 + mt * 16 + row16][col];
#pragma unroll
            for (int nt = 0; nt < 2; nt++)
                b[nt] = *(const bf16x8*)&BSP(cur)[wx * 32 + nt * 16 + row16][col];
#pragma unroll
            for (int mt = 0; mt < 4; mt++)
#pragma unroll
                for (int nt = 0; nt < 2; nt++)
                    acc[mt][nt] = __builtin_amdgcn_mfma_f32_16x16x32_bf16(a[mt], b[nt], acc[mt][nt], 0, 0, 0);
        }
        __builtin_amdgcn_s_barrier();
    }
#undef STAGE

    // ---- phase 2: K2 tile + relu(h) tile in LDS, contract 128 local o's ----
#pragma unroll
    for (int it = 0; it < 2; it++) {
        int gid = it * 512 + tid;                  // 1024 = 64 rows x 16 chunks
        int trow = gid >> 4, oc = (gid & 15) * 8;
        bf16x8 kv = *(const bf16x8*)&K2w[(size_t)trow * CH + mb * 128 + oc];
        *(bf16x8*)&K2L[trow][oc] = kv;
    }
#pragma unroll
    for (int mt = 0; mt < 4; mt++) {
        int ol = wy * 64 + mt * 16 + quad * 4;
        float4 bv = *(const float4*)&c1b[mb * 128 + ol];
#pragma unroll
        for (int nt = 0; nt < 2; nt++) {
            int n = wx * 32 + nt * 16 + row16;
            bf16x4 pk;
            pk[0] = (__bf16)fmaxf(acc[mt][nt][0] + bv.x, 0.f);
            pk[1] = (__bf16)fmaxf(acc[mt][nt][1] + bv.y, 0.f);
            pk[2] = (__bf16)fmaxf(acc[mt][nt][2] + bv.z, 0.f);
            pk[3] = (__bf16)fmaxf(acc[mt][nt][3] + bv.w, 0.f);
            *(bf16x4*)&HTL[n][ol] = pk;
        }
    }
    __syncthreads();

    // waves: tq = wave&3 covers t rows tq*16+row16; nhalf = wave>>2 covers n cols nhalf*64
    int tq = wave & 3, nhalf = wave >> 2;
    f4v acc2[4] = {};
#pragma unroll
    for (int ko = 0; ko < 4; ko++) {
        bf16x8 af = *(const bf16x8*)&K2L[tq * 16 + row16][ko * 32 + quad * 8];
#pragma unroll
        for (int nt = 0; nt < 4; nt++) {
            bf16x8 bf_ = *(const bf16x8*)&HTL[nhalf * 64 + nt * 16 + row16][ko * 32 + quad * 8];
            acc2[nt] = __builtin_amdgcn_mfma_f32_16x16x32_bf16(af, bf_, acc2[nt], 0, 0, 0);
        }
    }

    float* Qdst = sing ? Qs : Q;
    int ldq = sing ? 256 : LDQ;
    int nbase = sing ? (nb - ntp) * 128 : nb * 128;
    int t0 = tq * 16 + quad * 4;
#pragma unroll
    for (int nt = 0; nt < 4; nt++) {
        int n = nbase + nhalf * 64 + nt * 16 + row16;
#pragma unroll
        for (int r = 0; r < 4; r++)
            if (t0 + r < 49) atomicAdd(&Qdst[(size_t)(t0 + r) * ldq + n], acc2[nt][r]);
    }
#undef ASP
#undef BSP
#undef HTL
#undef K2L
}

// ---------------- output: one thread per (i,j) ----------------
__global__ void k_out(const float* __restrict__ Q, const float* __restrict__ Qs,
                      const float* __restrict__ Qc, const int* __restrict__ rank,
                      const int* __restrict__ counts, const float* b2,
                      float* __restrict__ outmaps) {
    __shared__ int rankL[256];
    __shared__ float QcL[49];
    int t = threadIdx.x, i = blockIdx.x;
    rankL[t] = rank[t];
    if (t < 49) QcL[t] = Qc[t];
    __syncthreads();
    int A = counts[0];
    int j = t;
    float acc = b2[0];
#pragma unroll
    for (int di = 0; di < 7; di++) {
        int p = i + di - 3;
        if ((unsigned)p > 255u) continue;
#pragma unroll
        for (int dj = 0; dj < 7; dj++) {
            int q = j + dj - 3;
            if ((unsigned)q > 255u) continue;
            int tt = di * 7 + dj;
            int a = min(p, q), bb = max(p, q);
            int ra = rankL[a], rb = rankL[bb];
            float val;
            if (ra >= 0) val = (rb >= 0) ? Q[(size_t)tt * LDQ + offA(ra, A) + (rb - ra)]
                                         : Qs[tt * 256 + a];
            else         val = (rb >= 0) ? Qs[tt * 256 + bb] : QcL[tt];
            acc += val;
        }
    }
    outmaps[i * 256 + j] = 1.0f / (1.0f + expf(-acc));
}

// ---------------- launch ----------------

extern "C" void kernel_launch(void* const* d_in, const int* in_sizes, int n_in,
                              void* d_out, int out_size, void* d_ws, size_t ws_size,
                              hipStream_t stream) {
    const float* att    = (const float*)d_in[0];
    const float* pooled = (const float*)d_in[1];
    const int*   am     = (const int*)d_in[2];
    const float* lin1_w = (const float*)d_in[3];
    const float* lin1_b = (const float*)d_in[4];
    const float* cls_w  = (const float*)d_in[5];
    const float* cls_b  = (const float*)d_in[6];
    const float* c1w    = (const float*)d_in[7];
    const float* c1b    = (const float*)d_in[8];
    const float* c2w    = (const float*)d_in[9];
    const float* c2b    = (const float*)d_in[10];
    float* out = (float*)d_out;
    char*  ws  = (char*)d_ws;

    // workspace (~75.8 MB)
    __bf16* A1p  = (__bf16*)(ws);                 // 1024*2048*2 = 4,194,304
    __bf16* K2w  = (__bf16*)(ws + 4194304);       // 64*1024*2   =   131,072
    float*  Q    = (float*) (ws + 4325376);       // 49*16384*4  = 3,211,264
    float*  Qs   = (float*) (ws + 7536640);       // 49*256*4    =    50,176  (contiguous with Q)
    float*  Qc   = (float*) (ws + 7586816);       // 49*4 (pad 256)
    int*    rank = (int*)   (ws + 7587072);       // 256*4 (pad 1024)
    float*  hid  = (float*) (ws + 7588096);       // 1024*4
    int*    counts=(int*)   (ws + 7592192);       // 16*4 (pad to 768)
    __bf16* featT= (__bf16*)(ws + 7592960);       // (PCAP+256)*2048*2 = 68,157,440

    k_prep<<<PB_TOTAL, 256, 0, stream>>>(att, am, c1w, c2w, c1b, pooled, lin1_w, lin1_b,
                                         rank, counts, featT, A1p, K2w, Qc, Q, hid);

    gemm_fused<<<dim3(9, 130), 512, 0, stream>>>(A1p, featT, K2w, c1b, counts, Q, Qs,
                                                 hid, cls_w, cls_b, out);

    k_out<<<256, 256, 0, stream>>>(Q, Qs, Qc, rank, counts, c2b, out + 2000);
}

// Round 11
// 158.208 us; speedup vs baseline: 1.3301x; 1.0305x over previous
//
#include <hip/hip_runtime.h>

typedef float  f4v    __attribute__((ext_vector_type(4)));
typedef __bf16 bf16x8 __attribute__((ext_vector_type(8)));
typedef __bf16 bf16x4 __attribute__((ext_vector_type(4)));

#define PCAP  16384   // max padded pair count (A<=180; actual A~127 -> Ppad 8192)
#define LDQ   16384
#define CH    1024
#define KI    2048    // interleaved K (diff/mul alternating)
#define KIT   32      // K iterations (BK=64)

__device__ __forceinline__ int offA(int r, int A) { return r * A - ((r * (r - 1)) >> 1); }

// ballot-scan of mask -> act[], A
__device__ __forceinline__ int mask_scan(const int* am, int t, int* act,
                                         unsigned long long* wm, int* wred) {
    int wave = t >> 6, lane = t & 63;
    int a = am[t];
    int sv = a;
#pragma unroll
    for (int d = 32; d; d >>= 1) sv += __shfl_down(sv, d);
    if (lane == 0) wred[wave] = sv;
    __syncthreads();
    int s = wred[0] + wred[1] + wred[2] + wred[3];
    int keep = (t != 0 && t != s && a != 0) ? 1 : 0;
    unsigned long long bm = __ballot(keep);
    if (lane == 0) wm[wave] = bm;
    __syncthreads();
    int base = 0, A = 0;
#pragma unroll
    for (int w = 0; w < 4; w++) {
        int pc = __popcll(wm[w]);
        if (w < wave) base += pc;
        A += pc;
    }
    if (keep) act[base + __popcll(bm & ((1ull << lane) - 1ull))] = t;
    __syncthreads();
    return A;
}

// ---------------- prep kernel: blockIdx ranges ----------------
#define PB_FEATP  0       // 2048: pair featT rows (8/block), self-scan
#define PB_FEATS  2048    // 32: single featT rows at [PCAP, PCAP+256)
#define PB_CVTA   2080    // 512: A1p interleaved bf16 conv of conv1_w
#define PB_K2     2592    // 256: K2w[64][1024]
#define PB_QCONST 2848    // 49
#define PB_ZERO   2897    // 797: zero Q + Qs (contiguous)
#define PB_SCAN   3694    // 1: rank/counts
#define PB_HID    3695    // 256: hid gemv
#define PB_TOTAL  3951

__global__ void k_prep(const float* __restrict__ att, const int* __restrict__ am,
                       const float* __restrict__ c1w, const float* __restrict__ c2w,
                       const float* __restrict__ c1b,
                       const float* __restrict__ pooled, const float* __restrict__ lin1_w,
                       const float* __restrict__ lin1_b,
                       int* rank, int* counts, __bf16* featT, __bf16* A1p, __bf16* K2w,
                       float* Qc, float* Qzero, float* hid) {
    int b = blockIdx.x, t = threadIdx.x;

    if (b < PB_FEATS) {
        // ---- pair featT rows: interleaved K, unified layout ----
        __shared__ int act[256];
        __shared__ unsigned long long wm[4];
        __shared__ int wred[4];
        int A = mask_scan(am, t, act, wm, wred);
        int P = (A * (A + 1)) >> 1;
        int Ppad = ((P + 127) >> 7) << 7;
        if (Ppad > PCAP) { Ppad = PCAP; P = PCAP; }
        int n0 = b * 8;
        if (n0 >= Ppad) return;
        int c0 = t * 4;                    // 4 original channels per thread
        float fA = (float)(2 * A + 1);
        for (int q = 0; q < 8; q++) {
            int n = n0 + q;
            bf16x8 ov;
            if (n < P && A > 0) {
                float disc = fmaxf(fA * fA - 8.0f * (float)n, 0.0f);
                int r = (int)floorf((fA - sqrtf(disc)) * 0.5f);
                r = min(A - 1, max(0, r));
                while (r > 0 && offA(r, A) > n) --r;
                while (r < A - 1 && offA(r + 1, A) <= n) ++r;
                int i = act[r], j = act[r + (n - offA(r, A))];
                float4 a = *(const float4*)&att[i * CH + c0];
                float4 bj = *(const float4*)&att[j * CH + c0];
                ov[0] = (__bf16)fabsf(a.x - bj.x); ov[1] = (__bf16)(a.x * bj.x);
                ov[2] = (__bf16)fabsf(a.y - bj.y); ov[3] = (__bf16)(a.y * bj.y);
                ov[4] = (__bf16)fabsf(a.z - bj.z); ov[5] = (__bf16)(a.z * bj.z);
                ov[6] = (__bf16)fabsf(a.w - bj.w); ov[7] = (__bf16)(a.w * bj.w);
            } else {
#pragma unroll
                for (int r8 = 0; r8 < 8; r8++) ov[r8] = (__bf16)0.0f;
            }
            *(bf16x8*)&featT[(size_t)n * KI + t * 8] = ov;
        }
    } else if (b < PB_CVTA) {
        // ---- single featT rows: |att[r]| at even slots, 0 at odd ----
        int r0 = (b - PB_FEATS) * 8;
        int c0 = t * 4;
        for (int q = 0; q < 8; q++) {
            int r = r0 + q;
            float4 a = *(const float4*)&att[r * CH + c0];
            bf16x8 ov;
            ov[0] = (__bf16)fabsf(a.x); ov[1] = (__bf16)0.f;
            ov[2] = (__bf16)fabsf(a.y); ov[3] = (__bf16)0.f;
            ov[4] = (__bf16)fabsf(a.z); ov[5] = (__bf16)0.f;
            ov[6] = (__bf16)fabsf(a.w); ov[7] = (__bf16)0.f;
            *(bf16x8*)&featT[(size_t)(PCAP + r) * KI + t * 8] = ov;
        }
    } else if (b < PB_K2) {
        int gid = (b - PB_CVTA) * 256 + t;  // 131072
        int o = gid >> 7, cw = (gid & 127) * 8;
        const float* wd = &c1w[o * 2048 + cw];
        const float* wmu = &c1w[o * 2048 + 1024 + cw];
        float4 d0 = *(const float4*)wd,  d1 = *(const float4*)(wd + 4);
        float4 m0 = *(const float4*)wmu, m1 = *(const float4*)(wmu + 4);
        bf16x8 v0, v1;
        v0[0] = (__bf16)d0.x; v0[1] = (__bf16)m0.x; v0[2] = (__bf16)d0.y; v0[3] = (__bf16)m0.y;
        v0[4] = (__bf16)d0.z; v0[5] = (__bf16)m0.z; v0[6] = (__bf16)d0.w; v0[7] = (__bf16)m0.w;
        v1[0] = (__bf16)d1.x; v1[1] = (__bf16)m1.x; v1[2] = (__bf16)d1.y; v1[3] = (__bf16)m1.y;
        v1[4] = (__bf16)d1.z; v1[5] = (__bf16)m1.z; v1[6] = (__bf16)d1.w; v1[7] = (__bf16)m1.w;
        *(bf16x8*)&A1p[o * 2048 + 2 * cw] = v0;
        *(bf16x8*)&A1p[o * 2048 + 2 * cw + 8] = v1;
    } else if (b < PB_QCONST) {
        int e = (b - PB_K2) * 256 + t;      // 65536 = 64*1024
        int trow = e >> 10, o = e & 1023;
        K2w[e] = (trow < 49) ? (__bf16)c2w[o * 49 + trow] : (__bf16)0.0f;
    } else if (b < PB_ZERO) {
        __shared__ float sh[256];
        int tap = b - PB_QCONST;
        float s = 0.f;
        for (int o = t; o < CH; o += 256) s += c2w[o * 49 + tap] * fmaxf(c1b[o], 0.f);
        sh[t] = s; __syncthreads();
        for (int d = 128; d; d >>= 1) { if (t < d) sh[t] += sh[t + d]; __syncthreads(); }
        if (t == 0) Qc[tap] = sh[0];
    } else if (b < PB_SCAN) {
        int idx = (b - PB_ZERO) * 256 + t;  // 203840 float4 = Q(49*16384) + Qs(49*256)
        if (idx < 203840) {
            float4 zv = {0.f, 0.f, 0.f, 0.f};
            ((float4*)Qzero)[idx] = zv;
        }
    } else if (b == PB_SCAN) {
        __shared__ int act[256];
        __shared__ unsigned long long wm[4];
        __shared__ int wred[4];
        int A = mask_scan(am, t, act, wm, wred);
        int wave = t >> 6, lane = t & 63;
        int s = wred[0] + wred[1] + wred[2] + wred[3];
        int keep = (t != 0 && t != s && am[t] != 0) ? 1 : 0;
        int base = 0;
#pragma unroll
        for (int w = 0; w < 4; w++) if (w < wave) base += __popcll(wm[w]);
        unsigned long long bm = wm[wave];
        rank[t] = keep ? (base + __popcll(bm & ((1ull << lane) - 1ull))) : -1;
        if (t == 0) {
            int P = (A * (A + 1)) >> 1;
            int Pp = ((P + 127) >> 7) << 7;
            if (Pp > PCAP) Pp = PCAP;
            counts[0] = A; counts[1] = P; counts[2] = Pp;
        }
    } else {
        int o = (b - PB_HID) * 4 + (t >> 6);
        int lane = t & 63;
        const float* row = lin1_w + (size_t)o * CH;
        float s = 0.f;
        for (int c = lane; c < CH; c += 64) s += pooled[c] * row[c];
        for (int d = 32; d; d >>= 1) s += __shfl_down(s, d);
        if (lane == 0) hid[o] = s + lin1_b[o];
    }
}

// ---------------- GEMM: 512 threads, 128M x 128N, BK=64, dbuf, vmcnt(4) ----------------
// grid (9, 136). x<8: GEMM; XCD g=(x+y)&7 (linear id x+9y mod 8) owns nb range
// [g*c_rt, (g+1)*c_rt): nb = g*c_rt + (y>>3), mb = y&7 (Latin square over (g, mb)).
// Each featT tile is read by exactly one XCD; A (4 MB) served by L2/L3.
// x==8: logits gemv (16 rows/block).
// Epilogue: in-LDS GEMM2 (K2 taps, 128 n-cols) -> atomicAdd into Q / Qs.
__global__ __launch_bounds__(512) void gemm_fused(
        const __bf16* __restrict__ A1p, const __bf16* __restrict__ featT,
        const __bf16* __restrict__ K2w, const float* __restrict__ c1b,
        const int* __restrict__ counts,
        float* __restrict__ Q, float* __restrict__ Qs,
        const float* __restrict__ hid, const float* __restrict__ cls_w,
        const float* __restrict__ cls_b, float* __restrict__ logits) {
    int x = blockIdx.x, y = blockIdx.y;
    int tid = threadIdx.x, wave = tid >> 6, lane = tid & 63;

    if (x == 8) {
#pragma unroll
        for (int rr = 0; rr < 2; rr++) {
            int o = y * 16 + wave * 2 + rr;
            if (o >= 2000) break;
            const float* row = cls_w + (size_t)o * CH;
            float s = 0.f;
            for (int c = lane; c < CH; c += 64) s += hid[c] * row[c];
            for (int d = 32; d; d >>= 1) s += __shfl_down(s, d);
            if (lane == 0) logits[o] = s + cls_b[o];
        }
        return;
    }

    int Ppad = counts[2];
    int ntp = Ppad >> 7;                 // 128-col pair tiles
    int ntiles = ntp + 2;                // + 2 single tiles (256 rows)
    int c_rt = (ntiles + 7) >> 3;
    int g = (x + y) & 7;                 // == XCD id under linear id (x + 9y) % 8
    int nbl = y >> 3, mb = y & 7;
    if (nbl >= c_rt) return;
    int nb = g * c_rt + nbl;
    if (nb >= ntiles) return;
    bool sing = (nb >= ntp);
    int brow = sing ? (PCAP + (nb - ntp) * 128) : nb * 128;

    __shared__ __align__(16) char smemraw[65536];
#define ASP(bsel) ((__bf16(*)[64])(smemraw + (bsel) * 16384))
#define BSP(bsel) ((__bf16(*)[64])(smemraw + 32768 + (bsel) * 16384))
#define HTL ((__bf16(*)[136])(smemraw))
#define K2L ((__bf16(*)[136])(smemraw + 34816))

    // staging: wave w stages A rows [w*16, w*16+16) and B rows [w*16, w*16+16), 2 instr each
    int lanerow = lane >> 3;
    int swchunk = ((lane & 7) ^ lanerow) * 8;
    const __bf16* srcA = A1p + (size_t)(mb * 128 + wave * 16 + lanerow) * KI + swchunk;
    const __bf16* srcB = featT + (size_t)(brow + wave * 16 + lanerow) * KI + swchunk;

    f4v acc[4][2] = {};
    int row16 = lane & 15, quad = lane >> 4;
    int wx = wave & 3, wy = wave >> 2;   // wave tile: rows wy*64+mt*16, cols wx*32+nt*16

#define STAGE(kt, bsel)                                                           \
    {                                                                             \
        const __bf16* sA = srcA + (kt) * 64;                                      \
        _Pragma("unroll")                                                         \
        for (int q = 0; q < 2; q++) {                                             \
            __builtin_amdgcn_global_load_lds(                                     \
                (const __attribute__((address_space(1))) void*)(sA + (size_t)q * 8 * KI), \
                (__attribute__((address_space(3))) void*)&ASP(bsel)[wave * 16 + q * 8][0], 16, 0, 0); \
        }                                                                         \
        const __bf16* sB = srcB + (kt) * 64;                                      \
        _Pragma("unroll")                                                         \
        for (int q = 0; q < 2; q++) {                                             \
            __builtin_amdgcn_global_load_lds(                                     \
                (const __attribute__((address_space(1))) void*)(sB + (size_t)q * 8 * KI), \
                (__attribute__((address_space(3))) void*)&BSP(bsel)[wave * 16 + q * 8][0], 16, 0, 0); \
        }                                                                         \
    }

    STAGE(0, 0);
    for (int kt = 0; kt < KIT; ++kt) {
        int cur = kt & 1;
        if (kt + 1 < KIT) {
            STAGE(kt + 1, cur ^ 1);
            __builtin_amdgcn_s_waitcnt(0xF74);   // vmcnt(4): prev batch done, next in flight
        } else {
            __builtin_amdgcn_s_waitcnt(0xF70);   // vmcnt(0)
        }
        __builtin_amdgcn_s_barrier();
#pragma unroll
        for (int ks = 0; ks < 2; ks++) {
            bf16x8 a[4], b[2];
            int col = ((ks * 4 + quad) ^ (row16 & 7)) * 8;
#pragma unroll
            for (int mt = 0; mt < 4; mt++)
                a[mt] = *(const bf16x8*)&ASP(cur)[wy * 64 + mt * 16 + row16][col];
#pragma unroll
            for (int nt = 0; nt < 2; nt++)
                b[nt] = *(const bf16x8*)&BSP(cur)[wx * 32 + nt * 16 + row16][col];
#pragma unroll
            for (int mt = 0; mt < 4; mt++)
#pragma unroll
                for (int nt = 0; nt < 2; nt++)
                    acc[mt][nt] = __builtin_amdgcn_mfma_f32_16x16x32_bf16(a[mt], b[nt], acc[mt][nt], 0, 0, 0);
        }
        __builtin_amdgcn_s_barrier();
    }
#undef STAGE

    // ---- phase 2: K2 tile + relu(h) tile in LDS, contract 128 local o's ----
#pragma unroll
    for (int it = 0; it < 2; it++) {
        int gid = it * 512 + tid;                  // 1024 = 64 rows x 16 chunks
        int trow = gid >> 4, oc = (gid & 15) * 8;
        bf16x8 kv = *(const bf16x8*)&K2w[(size_t)trow * CH + mb * 128 + oc];
        *(bf16x8*)&K2L[trow][oc] = kv;
    }
#pragma unroll
    for (int mt = 0; mt < 4; mt++) {
        int ol = wy * 64 + mt * 16 + quad * 4;
        float4 bv = *(const float4*)&c1b[mb * 128 + ol];
#pragma unroll
        for (int nt = 0; nt < 2; nt++) {
            int n = wx * 32 + nt * 16 + row16;
            bf16x4 pk;
            pk[0] = (__bf16)fmaxf(acc[mt][nt][0] + bv.x, 0.f);
            pk[1] = (__bf16)fmaxf(acc[mt][nt][1] + bv.y, 0.f);
            pk[2] = (__bf16)fmaxf(acc[mt][nt][2] + bv.z, 0.f);
            pk[3] = (__bf16)fmaxf(acc[mt][nt][3] + bv.w, 0.f);
            *(bf16x4*)&HTL[n][ol] = pk;
        }
    }
    __syncthreads();

    // waves: tq = wave&3 covers t rows tq*16+row16; nhalf = wave>>2 covers n cols nhalf*64
    int tq = wave & 3, nhalf = wave >> 2;
    f4v acc2[4] = {};
#pragma unroll
    for (int ko = 0; ko < 4; ko++) {
        bf16x8 af = *(const bf16x8*)&K2L[tq * 16 + row16][ko * 32 + quad * 8];
#pragma unroll
        for (int nt = 0; nt < 4; nt++) {
            bf16x8 bf_ = *(const bf16x8*)&HTL[nhalf * 64 + nt * 16 + row16][ko * 32 + quad * 8];
            acc2[nt] = __builtin_amdgcn_mfma_f32_16x16x32_bf16(af, bf_, acc2[nt], 0, 0, 0);
        }
    }

    float* Qdst = sing ? Qs : Q;
    int ldq = sing ? 256 : LDQ;
    int nbase = sing ? (nb - ntp) * 128 : nb * 128;
    int t0 = tq * 16 + quad * 4;
#pragma unroll
    for (int nt = 0; nt < 4; nt++) {
        int n = nbase + nhalf * 64 + nt * 16 + row16;
#pragma unroll
        for (int r = 0; r < 4; r++)
            if (t0 + r < 49) atomicAdd(&Qdst[(size_t)(t0 + r) * ldq + n], acc2[nt][r]);
    }
#undef ASP
#undef BSP
#undef HTL
#undef K2L
}

// ---------------- output: one thread per (i,j) ----------------
__global__ void k_out(const float* __restrict__ Q, const float* __restrict__ Qs,
                      const float* __restrict__ Qc, const int* __restrict__ rank,
                      const int* __restrict__ counts, const float* b2,
                      float* __restrict__ outmaps) {
    __shared__ int rankL[256];
    __shared__ float QcL[49];
    int t = threadIdx.x, i = blockIdx.x;
    rankL[t] = rank[t];
    if (t < 49) QcL[t] = Qc[t];
    __syncthreads();
    int A = counts[0];
    int j = t;
    float acc = b2[0];
#pragma unroll
    for (int di = 0; di < 7; di++) {
        int p = i + di - 3;
        if ((unsigned)p > 255u) continue;
#pragma unroll
        for (int dj = 0; dj < 7; dj++) {
            int q = j + dj - 3;
            if ((unsigned)q > 255u) continue;
            int tt = di * 7 + dj;
            int a = min(p, q), bb = max(p, q);
            int ra = rankL[a], rb = rankL[bb];
            float val;
            if (ra >= 0) val = (rb >= 0) ? Q[(size_t)tt * LDQ + offA(ra, A) + (rb - ra)]
                                         : Qs[tt * 256 + a];
            else         val = (rb >= 0) ? Qs[tt * 256 + bb] : QcL[tt];
            acc += val;
        }
    }
    outmaps[i * 256 + j] = 1.0f / (1.0f + expf(-acc));
}

// ---------------- launch ----------------

extern "C" void kernel_launch(void* const* d_in, const int* in_sizes, int n_in,
                              void* d_out, int out_size, void* d_ws, size_t ws_size,
                              hipStream_t stream) {
    const float* att    = (const float*)d_in[0];
    const float* pooled = (const float*)d_in[1];
    const int*   am     = (const int*)d_in[2];
    const float* lin1_w = (const float*)d_in[3];
    const float* lin1_b = (const float*)d_in[4];
    const float* cls_w  = (const float*)d_in[5];
    const float* cls_b  = (const float*)d_in[6];
    const float* c1w    = (const float*)d_in[7];
    const float* c1b    = (const float*)d_in[8];
    const float* c2w    = (const float*)d_in[9];
    const float* c2b    = (const float*)d_in[10];
    float* out = (float*)d_out;
    char*  ws  = (char*)d_ws;

    // workspace (~75.8 MB)
    __bf16* A1p  = (__bf16*)(ws);                 // 1024*2048*2 = 4,194,304
    __bf16* K2w  = (__bf16*)(ws + 4194304);       // 64*1024*2   =   131,072
    float*  Q    = (float*) (ws + 4325376);       // 49*16384*4  = 3,211,264
    float*  Qs   = (float*) (ws + 7536640);       // 49*256*4    =    50,176  (contiguous with Q)
    float*  Qc   = (float*) (ws + 7586816);       // 49*4 (pad 256)
    int*    rank = (int*)   (ws + 7587072);       // 256*4 (pad 1024)
    float*  hid  = (float*) (ws + 7588096);       // 1024*4
    int*    counts=(int*)   (ws + 7592192);       // 16*4 (pad to 768)
    __bf16* featT= (__bf16*)(ws + 7592960);       // (PCAP+256)*2048*2 = 68,157,440

    k_prep<<<PB_TOTAL, 256, 0, stream>>>(att, am, c1w, c2w, c1b, pooled, lin1_w, lin1_b,
                                         rank, counts, featT, A1p, K2w, Qc, Q, hid);

    gemm_fused<<<dim3(9, 136), 512, 0, stream>>>(A1p, featT, K2w, c1b, counts, Q, Qs,
                                                 hid, cls_w, cls_b, out);

    k_out<<<256, 256, 0, stream>>>(Q, Qs, Qc, rank, counts, c2b, out + 2000);
}